// Round 4
// baseline (199.132 us; speedup 1.0000x reference)
//
#include <hip/hip_runtime.h>

#define ALPHA 0.2f
#define BATCH 8
#define NN    2048
#define FD    256

typedef __attribute__((ext_vector_type(8))) short short8;
typedef __attribute__((ext_vector_type(4))) float f32x4;

__device__ __forceinline__ unsigned short f2bf(float f){
  unsigned u = __builtin_bit_cast(unsigned, f);
  return (unsigned short)((u + 0x7FFFu + ((u>>16)&1u)) >> 16);   // RTN-even
}
__device__ __forceinline__ float dot4(float4 a, float4 b){
  return a.x*b.x + a.y*b.y + a.z*b.z + a.w*b.w;
}

// ---------------------------------------------------------------------------
// K0: w_src = W @ a_src, w_dst = W @ a_dst (exact fp32), WT[o][k] = bf16(W[k][o])
// ---------------------------------------------------------------------------
__global__ __launch_bounds__(64) void prep_w(
    const float* __restrict__ W, const float* __restrict__ a,
    float* __restrict__ w_src, float* __restrict__ w_dst,
    unsigned short* __restrict__ WT)
{
  const int k = blockIdx.x;
  const int l = threadIdx.x;
  float4 wv = *(const float4*)(W + k*FD + l*4);
  float4 as = *(const float4*)(a + l*4);
  float4 ad = *(const float4*)(a + FD + l*4);
  float s = dot4(wv, as);
  float d = dot4(wv, ad);
#pragma unroll
  for (int m=1;m<64;m<<=1){ s += __shfl_xor(s, m); d += __shfl_xor(d, m); }
  if (l == 0){ w_src[k] = s; w_dst[k] = d; }
  WT[(l*4+0)*FD + k] = f2bf(wv.x);
  WT[(l*4+1)*FD + k] = f2bf(wv.y);
  WT[(l*4+2)*FD + k] = f2bf(wv.z);
  WT[(l*4+3)*FD + k] = f2bf(wv.w);
}

// ---------------------------------------------------------------------------
// K0b: e_src/e_dst fp32 per row; xb = bf16(x)
// ---------------------------------------------------------------------------
__global__ __launch_bounds__(256) void prep_x(
    const float* __restrict__ x,
    const float* __restrict__ w_src, const float* __restrict__ w_dst,
    unsigned short* __restrict__ xb,
    float* __restrict__ e_src, float* __restrict__ e_dst)
{
  const int row = blockIdx.x*4 + (threadIdx.x >> 6);
  const int l = threadIdx.x & 63;
  float4 xv = *(const float4*)(x + (size_t)row*FD + l*4);
  float4 ws = *(const float4*)(w_src + l*4);
  float4 wd = *(const float4*)(w_dst + l*4);
  float s = dot4(xv, ws);
  float d = dot4(xv, wd);
#pragma unroll
  for (int m=1;m<64;m<<=1){ s += __shfl_xor(s, m); d += __shfl_xor(d, m); }
  if (l == 0){ e_src[row] = s; e_dst[row] = d; }
  uint2 u;
  u.x = (unsigned)f2bf(xv.x) | ((unsigned)f2bf(xv.y)<<16);
  u.y = (unsigned)f2bf(xv.z) | ((unsigned)f2bf(xv.w)<<16);
  *(uint2*)(xb + (size_t)row*FD + l*4) = u;
}

// ---------------------------------------------------------------------------
// K1: h = x @ W, bf16 MFMA, output transposed hT[b][o][n].
// ---------------------------------------------------------------------------
__global__ __launch_bounds__(256) void gemm_h(
    const unsigned short* __restrict__ xb,
    const unsigned short* __restrict__ WT,
    unsigned short* __restrict__ hT)
{
  const int tid = threadIdx.x;
  const int w = tid >> 6, l = tid & 63;
  const int r16 = l & 15, g = l >> 4;
  const int row0 = blockIdx.x << 4;

  f32x4 acc[4];
#pragma unroll
  for (int c=0;c<4;c++) acc[c] = (f32x4){0.f,0.f,0.f,0.f};

  const unsigned short* xrow  = xb + (size_t)(row0 + r16)*FD + g*8;
  const unsigned short* wbase = WT + (size_t)(w*64 + r16)*FD + g*8;
#pragma unroll
  for (int s=0;s<8;s++){
    short8 afrag = __builtin_bit_cast(short8, *(const int4*)(xrow + s*32));
#pragma unroll
    for (int cl=0;cl<4;cl++){
      int4 bv = *(const int4*)(wbase + (size_t)cl*16*FD + s*32);
      acc[cl] = __builtin_amdgcn_mfma_f32_16x16x32_bf16(
                  afrag, __builtin_bit_cast(short8, bv), acc[cl], 0, 0, 0);
    }
  }
  const int b  = row0 >> 11;
  const int nb = (row0 + g*4) & (NN-1);
  unsigned short* hTB = hT + (size_t)b*FD*NN;
#pragma unroll
  for (int cl=0;cl<4;cl++){
    const int o = w*64 + cl*16 + r16;
    uint2 u;
    u.x = (unsigned)f2bf(acc[cl][0]) | ((unsigned)f2bf(acc[cl][1])<<16);
    u.y = (unsigned)f2bf(acc[cl][2]) | ((unsigned)f2bf(acc[cl][3])<<16);
    *(uint2*)(hTB + (size_t)o*NN + nb) = u;
  }
}

// ---------------------------------------------------------------------------
// K2: fused scores + exp + PV + normalize + ELU.
// Grid 1024 = 8 XCD-affine batches x 128 n-tiles of 16 rows. 4 waves/block,
// m-split: wave q owns m in [512q, 512q+512), 16 steps of 32. No barriers /
// no LDS in the main loop (B-frags direct from L2-resident hT slab, adj
// reg-prefetched depth 2). 4 blocks/CU -> 4 waves/SIMD hide L2/HBM latency.
// Epilogue: LDS combine of the 4 partial acc + rowsums; wave 0 finalizes.
// ---------------------------------------------------------------------------
__global__ __launch_bounds__(256,4) void gat_fused(
    const int* __restrict__ adj,
    const float* __restrict__ e_src,
    const float* __restrict__ e_dst,
    const unsigned short* __restrict__ hT,
    float* __restrict__ out)
{
  __shared__ f32x4 red[8][3][64];                 // 24 KB
  __shared__ float rsum[4][16];

  const int tid = threadIdx.x;
  const int q   = tid >> 6;            // m-quarter
  const int l   = tid & 63;
  const int r16 = l & 15, g = l >> 4;
  const int b   = blockIdx.x & 7;      // XCD-affine batch
  const int n0  = (blockIdx.x >> 3) << 4;

  const int* adjR = adj + (size_t)(b*NN + n0 + r16)*NN + q*512 + g*8;
  const float* edB = e_dst + b*NN + q*512 + g*8;
  const unsigned short* hTB = hT + (size_t)b*FD*NN + (size_t)r16*NN + q*512 + g*8;
  const float es = e_src[b*NN + n0 + r16];

  f32x4 acc[16];
#pragma unroll
  for (int c=0;c<16;c++) acc[c] = (f32x4){0.f,0.f,0.f,0.f};
  float ps = 0.f;

  auto mkp = [&](int4 a0,int4 a1,float4 e0,float4 e1)->short8{
    int   ai[8] = {a0.x,a0.y,a0.z,a0.w,a1.x,a1.y,a1.z,a1.w};
    float ev[8] = {e0.x,e0.y,e0.z,e0.w,e1.x,e1.y,e1.z,e1.w};
    unsigned pt[8];
#pragma unroll
    for (int j=0;j<8;j++){
      float s = es + ev[j];
      s = fmaxf(s, ALPHA*s);                       // leaky relu
      float p = __expf(s);
      p = (ai[j] > 0) ? p : 0.f;
      unsigned ub = __builtin_bit_cast(unsigned, p) & 0xFFFF0000u;
      ps += __builtin_bit_cast(float, ub);         // rowsum of truncated P
      pt[j] = ub;
    }
    union { short8 v; unsigned u[4]; } A;
#pragma unroll
    for (int j=0;j<4;j++) A.u[j] = pt[2*j+1] | (pt[2*j] >> 16);
    return A.v;
  };
  auto mfma16 = [&](short8 pa, int t){
#pragma unroll
    for (int c=0;c<16;c++){
      int4 bv = *(const int4*)(hTB + (size_t)c*16*NN + t*32);
      acc[c] = __builtin_amdgcn_mfma_f32_16x16x32_bf16(
                 pa, __builtin_bit_cast(short8, bv), acc[c], 0, 0, 0);
    }
  };

  int4 ajA0,ajA1,ajB0,ajB1;
  { const int* p = adjR;      ajA0 = *(const int4*)p; ajA1 = *(const int4*)(p+4); }
  { const int* p = adjR + 32; ajB0 = *(const int4*)p; ajB1 = *(const int4*)(p+4); }

  for (int t = 0; t < 16; t += 2){
    const int tA = (t+2 < 16) ? t+2 : 0;
    const int tB = (t+3 < 16) ? t+3 : 0;
    // step t
    {
      const float* p = edB + t*32;
      float4 e0 = *(const float4*)p, e1 = *(const float4*)(p+4);
      short8 pa = mkp(ajA0, ajA1, e0, e1);
      const int* ap = adjR + tA*32;
      ajA0 = *(const int4*)ap; ajA1 = *(const int4*)(ap+4);
      mfma16(pa, t);
    }
    // step t+1
    {
      const float* p = edB + (t+1)*32;
      float4 e0 = *(const float4*)p, e1 = *(const float4*)(p+4);
      short8 pa = mkp(ajB0, ajB1, e0, e1);
      const int* ap = adjR + tB*32;
      ajB0 = *(const int4*)ap; ajB1 = *(const int4*)(ap+4);
      mfma16(pa, t+1);
    }
  }

  // ---- partial rowsum: full m-quarter sum for row r16, all lanes ----
  float rs = ps;
  rs += __shfl_xor(rs, 16);
  rs += __shfl_xor(rs, 32);
  if (l < 16) rsum[q][l] = rs;

  // ---- combine round 0: c in [0,8) ----
  if (q > 0){
#pragma unroll
    for (int c=0;c<8;c++) red[c][q-1][l] = acc[c];
  }
  __syncthreads();

  if (q == 0){
    float tot = rsum[0][r16] + rsum[1][r16] + rsum[2][r16] + rsum[3][r16];
    float inv_[4];
#pragma unroll
    for (int r=0;r<4;r++) inv_[r] = 1.0f / __shfl(tot, g*4 + r);
    float* outB = out + (size_t)(b*NN + n0)*FD;
#pragma unroll
    for (int c=0;c<8;c++){
      f32x4 v = acc[c] + red[c][0][l] + red[c][1][l] + red[c][2][l];
#pragma unroll
      for (int r=0;r<4;r++){
        float o = v[r] * inv_[r];
        o = o > 0.f ? o : (__expf(o) - 1.f);       // ELU
        outB[(size_t)(g*4 + r)*FD + c*16 + r16] = o;
      }
    }
  }
  __syncthreads();

  // ---- combine round 1: c in [8,16) ----
  if (q > 0){
#pragma unroll
    for (int c=0;c<8;c++) red[c][q-1][l] = acc[8+c];
  }
  __syncthreads();

  if (q == 0){
    float tot = rsum[0][r16] + rsum[1][r16] + rsum[2][r16] + rsum[3][r16];
    float inv_[4];
#pragma unroll
    for (int r=0;r<4;r++) inv_[r] = 1.0f / __shfl(tot, g*4 + r);
    float* outB = out + (size_t)(b*NN + n0)*FD;
#pragma unroll
    for (int c=0;c<8;c++){
      f32x4 v = acc[8+c] + red[c][0][l] + red[c][1][l] + red[c][2][l];
#pragma unroll
      for (int r=0;r<4;r++){
        float o = v[r] * inv_[r];
        o = o > 0.f ? o : (__expf(o) - 1.f);       // ELU
        outB[(size_t)(g*4 + r)*FD + (8+c)*16 + r16] = o;
      }
    }
  }
}

// ---------------------------------------------------------------------------
extern "C" void kernel_launch(void* const* d_in, const int* in_sizes, int n_in,
                              void* d_out, int out_size, void* d_ws, size_t ws_size,
                              hipStream_t stream)
{
  const float* x   = (const float*)d_in[0];
  const int*   adj = (const int*)  d_in[1];
  const float* W   = (const float*)d_in[2];
  const float* a   = (const float*)d_in[3];
  float* out = (float*)d_out;

  char* ws = (char*)d_ws;
  size_t off = 0;
  auto alloc = [&](size_t bytes)->char*{
    char* p = ws + off; off += (bytes + 255) & ~(size_t)255; return p;
  };
  unsigned short* WT    = (unsigned short*)alloc((size_t)FD*FD*2);
  float*          w_src = (float*)alloc(FD*4);
  float*          w_dst = (float*)alloc(FD*4);
  float*          e_src = (float*)alloc((size_t)BATCH*NN*4);
  float*          e_dst = (float*)alloc((size_t)BATCH*NN*4);
  unsigned short* xb    = (unsigned short*)alloc((size_t)BATCH*NN*FD*2);
  unsigned short* hT    = (unsigned short*)alloc((size_t)BATCH*NN*FD*2);

  prep_w   <<<FD,              64,  0, stream>>>(W, a, w_src, w_dst, WT);
  prep_x   <<<(BATCH*NN)/4,    256, 0, stream>>>(x, w_src, w_dst, xb, e_src, e_dst);
  gemm_h   <<<(BATCH*NN)/16,   256, 0, stream>>>(xb, WT, hT);
  gat_fused<<<(BATCH*NN)/16,   256, 0, stream>>>(adj, e_src, e_dst, hT, out);
}

// Round 5
// 147.810 us; speedup vs baseline: 1.3472x; 1.3472x over previous
//
#include <hip/hip_runtime.h>

#define ALPHA 0.2f
#define BATCH 8
#define NN    2048
#define FD    256
// hT layout: [b][t=m/32][o=0..255][mj=0..31], short. 8192 shorts (16KB) per tile.
#define TILE_SH 8192
#define BSLAB   (FD*NN)          // shorts per batch slab (1 MB)

typedef __attribute__((ext_vector_type(8))) short short8;
typedef __attribute__((ext_vector_type(4))) float f32x4;

__device__ __forceinline__ unsigned short f2bf(float f){
  unsigned u = __builtin_bit_cast(unsigned, f);
  return (unsigned short)((u + 0x7FFFu + ((u>>16)&1u)) >> 16);   // RTN-even
}
__device__ __forceinline__ float dot4(float4 a, float4 b){
  return a.x*b.x + a.y*b.y + a.z*b.z + a.w*b.w;
}

// ---------------------------------------------------------------------------
// K0: w_src = W @ a_src, w_dst = W @ a_dst (exact fp32), WT[o][k] = bf16(W[k][o])
// ---------------------------------------------------------------------------
__global__ __launch_bounds__(64) void prep_w(
    const float* __restrict__ W, const float* __restrict__ a,
    float* __restrict__ w_src, float* __restrict__ w_dst,
    unsigned short* __restrict__ WT)
{
  const int k = blockIdx.x;
  const int l = threadIdx.x;
  float4 wv = *(const float4*)(W + k*FD + l*4);
  float4 as = *(const float4*)(a + l*4);
  float4 ad = *(const float4*)(a + FD + l*4);
  float s = dot4(wv, as);
  float d = dot4(wv, ad);
#pragma unroll
  for (int m=1;m<64;m<<=1){ s += __shfl_xor(s, m); d += __shfl_xor(d, m); }
  if (l == 0){ w_src[k] = s; w_dst[k] = d; }
  WT[(l*4+0)*FD + k] = f2bf(wv.x);
  WT[(l*4+1)*FD + k] = f2bf(wv.y);
  WT[(l*4+2)*FD + k] = f2bf(wv.z);
  WT[(l*4+3)*FD + k] = f2bf(wv.w);
}

// ---------------------------------------------------------------------------
// K0b: e_src/e_dst fp32 per row; xb = bf16(x)
// ---------------------------------------------------------------------------
__global__ __launch_bounds__(256) void prep_x(
    const float* __restrict__ x,
    const float* __restrict__ w_src, const float* __restrict__ w_dst,
    unsigned short* __restrict__ xb,
    float* __restrict__ e_src, float* __restrict__ e_dst)
{
  const int row = blockIdx.x*4 + (threadIdx.x >> 6);
  const int l = threadIdx.x & 63;
  float4 xv = *(const float4*)(x + (size_t)row*FD + l*4);
  float4 ws = *(const float4*)(w_src + l*4);
  float4 wd = *(const float4*)(w_dst + l*4);
  float s = dot4(xv, ws);
  float d = dot4(xv, wd);
#pragma unroll
  for (int m=1;m<64;m<<=1){ s += __shfl_xor(s, m); d += __shfl_xor(d, m); }
  if (l == 0){ e_src[row] = s; e_dst[row] = d; }
  uint2 u;
  u.x = (unsigned)f2bf(xv.x) | ((unsigned)f2bf(xv.y)<<16);
  u.y = (unsigned)f2bf(xv.z) | ((unsigned)f2bf(xv.w)<<16);
  *(uint2*)(xb + (size_t)row*FD + l*4) = u;
}

// ---------------------------------------------------------------------------
// K1: h = x @ W, bf16 MFMA, output in fragment-linear tiled layout:
//     hTt[b][t=n/32][o][n&31]
// ---------------------------------------------------------------------------
__global__ __launch_bounds__(256) void gemm_h(
    const unsigned short* __restrict__ xb,
    const unsigned short* __restrict__ WT,
    unsigned short* __restrict__ hT)
{
  const int tid = threadIdx.x;
  const int w = tid >> 6, l = tid & 63;
  const int r16 = l & 15, g = l >> 4;
  const int row0 = blockIdx.x << 4;

  f32x4 acc[4];
#pragma unroll
  for (int c=0;c<4;c++) acc[c] = (f32x4){0.f,0.f,0.f,0.f};

  const unsigned short* xrow  = xb + (size_t)(row0 + r16)*FD + g*8;
  const unsigned short* wbase = WT + (size_t)(w*64 + r16)*FD + g*8;
#pragma unroll
  for (int s=0;s<8;s++){
    short8 afrag = __builtin_bit_cast(short8, *(const int4*)(xrow + s*32));
#pragma unroll
    for (int cl=0;cl<4;cl++){
      int4 bv = *(const int4*)(wbase + (size_t)cl*16*FD + s*32);
      acc[cl] = __builtin_amdgcn_mfma_f32_16x16x32_bf16(
                  afrag, __builtin_bit_cast(short8, bv), acc[cl], 0, 0, 0);
    }
  }
  const int b    = row0 >> 11;
  const int nloc = row0 & (NN-1);
  const int t    = nloc >> 5;                 // block-constant tile index
  const int mj   = (nloc & 31) + g*4;         // 4 consecutive m's
  unsigned short* dst = hT + (size_t)b*BSLAB + (size_t)t*TILE_SH + mj;
#pragma unroll
  for (int cl=0;cl<4;cl++){
    const int o = w*64 + cl*16 + r16;
    uint2 u;
    u.x = (unsigned)f2bf(acc[cl][0]) | ((unsigned)f2bf(acc[cl][1])<<16);
    u.y = (unsigned)f2bf(acc[cl][2]) | ((unsigned)f2bf(acc[cl][3])<<16);
    *(uint2*)(dst + o*32) = u;
  }
}

// ---------------------------------------------------------------------------
// K2: fused scores + exp + PV + normalize + ELU.
// Grid 1024 = 8 XCD-affine batches x 128 n-tiles of 16 rows. 4 waves/block,
// m-split: wave q owns m in [512q, 512q+512), 16 steps of 32. No barriers /
// no LDS in main loop. B-frag load (c,t) = one fully-contiguous 1 KB wave
// burst from the L2-resident tiled hT slab. adj reg-prefetched depth 2.
// Epilogue: LDS combine of the 4 partial acc + rowsums; wave 0 finalizes.
// ---------------------------------------------------------------------------
__global__ __launch_bounds__(256,4) void gat_fused(
    const int* __restrict__ adj,
    const float* __restrict__ e_src,
    const float* __restrict__ e_dst,
    const unsigned short* __restrict__ hT,
    float* __restrict__ out)
{
  __shared__ f32x4 red[8][3][64];                 // 24 KB
  __shared__ float rsum[4][16];

  const int tid = threadIdx.x;
  const int q   = tid >> 6;            // m-quarter
  const int l   = tid & 63;
  const int r16 = l & 15, g = l >> 4;
  const int b   = blockIdx.x & 7;      // XCD-affine batch
  const int n0  = (blockIdx.x >> 3) << 4;

  const int* adjR = adj + (size_t)(b*NN + n0 + r16)*NN + q*512 + g*8;
  const float* edB = e_dst + b*NN + q*512 + g*8;
  // fragment base: lane offset r16*32 + g*8 within each 1KB o-subtile
  const unsigned short* hTB = hT + (size_t)b*BSLAB + (size_t)q*16*TILE_SH
                                 + r16*32 + g*8;
  const float es = e_src[b*NN + n0 + r16];

  f32x4 acc[16];
#pragma unroll
  for (int c=0;c<16;c++) acc[c] = (f32x4){0.f,0.f,0.f,0.f};
  float ps = 0.f;

  auto mkp = [&](int4 a0,int4 a1,float4 e0,float4 e1)->short8{
    int   ai[8] = {a0.x,a0.y,a0.z,a0.w,a1.x,a1.y,a1.z,a1.w};
    float ev[8] = {e0.x,e0.y,e0.z,e0.w,e1.x,e1.y,e1.z,e1.w};
    unsigned pt[8];
#pragma unroll
    for (int j=0;j<8;j++){
      float s = es + ev[j];
      s = fmaxf(s, ALPHA*s);                       // leaky relu
      float p = __expf(s);
      p = (ai[j] > 0) ? p : 0.f;
      unsigned ub = __builtin_bit_cast(unsigned, p) & 0xFFFF0000u;
      ps += __builtin_bit_cast(float, ub);         // rowsum of truncated P
      pt[j] = ub;
    }
    union { short8 v; unsigned u[4]; } A;
#pragma unroll
    for (int j=0;j<4;j++) A.u[j] = pt[2*j+1] | (pt[2*j] >> 16);
    return A.v;
  };
  auto mfma16 = [&](short8 pa, int t){
    const unsigned short* hb = hTB + (size_t)t*TILE_SH;
#pragma unroll
    for (int c=0;c<16;c++){
      int4 bv = *(const int4*)(hb + c*512);
      acc[c] = __builtin_amdgcn_mfma_f32_16x16x32_bf16(
                 pa, __builtin_bit_cast(short8, bv), acc[c], 0, 0, 0);
    }
  };

  int4 ajA0,ajA1,ajB0,ajB1;
  { const int* p = adjR;      ajA0 = *(const int4*)p; ajA1 = *(const int4*)(p+4); }
  { const int* p = adjR + 32; ajB0 = *(const int4*)p; ajB1 = *(const int4*)(p+4); }

  for (int t = 0; t < 16; t += 2){
    const int tA = (t+2 < 16) ? t+2 : 0;
    const int tB = (t+3 < 16) ? t+3 : 0;
    // step t
    {
      const float* p = edB + t*32;
      float4 e0 = *(const float4*)p, e1 = *(const float4*)(p+4);
      short8 pa = mkp(ajA0, ajA1, e0, e1);
      const int* ap = adjR + tA*32;
      ajA0 = *(const int4*)ap; ajA1 = *(const int4*)(ap+4);
      mfma16(pa, t);
    }
    // step t+1
    {
      const float* p = edB + (t+1)*32;
      float4 e0 = *(const float4*)p, e1 = *(const float4*)(p+4);
      short8 pa = mkp(ajB0, ajB1, e0, e1);
      const int* ap = adjR + tB*32;
      ajB0 = *(const int4*)ap; ajB1 = *(const int4*)(ap+4);
      mfma16(pa, t+1);
    }
  }

  // ---- partial rowsum: full m-quarter sum for row r16, all lanes ----
  float rs = ps;
  rs += __shfl_xor(rs, 16);
  rs += __shfl_xor(rs, 32);
  if (l < 16) rsum[q][l] = rs;

  // ---- combine round 0: c in [0,8) ----
  if (q > 0){
#pragma unroll
    for (int c=0;c<8;c++) red[c][q-1][l] = acc[c];
  }
  __syncthreads();

  if (q == 0){
    float tot = rsum[0][r16] + rsum[1][r16] + rsum[2][r16] + rsum[3][r16];
    float inv_[4];
#pragma unroll
    for (int r=0;r<4;r++) inv_[r] = 1.0f / __shfl(tot, g*4 + r);
    float* outB = out + (size_t)(b*NN + n0)*FD;
#pragma unroll
    for (int c=0;c<8;c++){
      f32x4 v = acc[c] + red[c][0][l] + red[c][1][l] + red[c][2][l];
#pragma unroll
      for (int r=0;r<4;r++){
        float o = v[r] * inv_[r];
        o = o > 0.f ? o : (__expf(o) - 1.f);       // ELU
        outB[(size_t)(g*4 + r)*FD + c*16 + r16] = o;
      }
    }
  }
  __syncthreads();

  // ---- combine round 1: c in [8,16) ----
  if (q > 0){
#pragma unroll
    for (int c=0;c<8;c++) red[c][q-1][l] = acc[8+c];
  }
  __syncthreads();

  if (q == 0){
    float tot = rsum[0][r16] + rsum[1][r16] + rsum[2][r16] + rsum[3][r16];
    float inv_[4];
#pragma unroll
    for (int r=0;r<4;r++) inv_[r] = 1.0f / __shfl(tot, g*4 + r);
    float* outB = out + (size_t)(b*NN + n0)*FD;
#pragma unroll
    for (int c=0;c<8;c++){
      f32x4 v = acc[8+c] + red[c][0][l] + red[c][1][l] + red[c][2][l];
#pragma unroll
      for (int r=0;r<4;r++){
        float o = v[r] * inv_[r];
        o = o > 0.f ? o : (__expf(o) - 1.f);       // ELU
        outB[(size_t)(g*4 + r)*FD + (8+c)*16 + r16] = o;
      }
    }
  }
}

// ---------------------------------------------------------------------------
extern "C" void kernel_launch(void* const* d_in, const int* in_sizes, int n_in,
                              void* d_out, int out_size, void* d_ws, size_t ws_size,
                              hipStream_t stream)
{
  const float* x   = (const float*)d_in[0];
  const int*   adj = (const int*)  d_in[1];
  const float* W   = (const float*)d_in[2];
  const float* a   = (const float*)d_in[3];
  float* out = (float*)d_out;

  char* ws = (char*)d_ws;
  size_t off = 0;
  auto alloc = [&](size_t bytes)->char*{
    char* p = ws + off; off += (bytes + 255) & ~(size_t)255; return p;
  };
  unsigned short* WT    = (unsigned short*)alloc((size_t)FD*FD*2);
  float*          w_src = (float*)alloc(FD*4);
  float*          w_dst = (float*)alloc(FD*4);
  float*          e_src = (float*)alloc((size_t)BATCH*NN*4);
  float*          e_dst = (float*)alloc((size_t)BATCH*NN*4);
  unsigned short* xb    = (unsigned short*)alloc((size_t)BATCH*NN*FD*2);
  unsigned short* hT    = (unsigned short*)alloc((size_t)BATCH*NN*FD*2);

  prep_w   <<<FD,              64,  0, stream>>>(W, a, w_src, w_dst, WT);
  prep_x   <<<(BATCH*NN)/4,    256, 0, stream>>>(x, w_src, w_dst, xb, e_src, e_dst);
  gemm_h   <<<(BATCH*NN)/16,   256, 0, stream>>>(xb, WT, hT);
  gat_fused<<<(BATCH*NN)/16,   256, 0, stream>>>(adj, e_src, e_dst, hT, out);
}

// Round 7
// 131.306 us; speedup vs baseline: 1.5165x; 1.1257x over previous
//
#include <hip/hip_runtime.h>

#define ALPHA 0.2f
#define BATCH 8
#define NN    2048
#define FD    256
// hT layout: [b][t=m/32][o=0..255][mj=0..31], short. 8192 shorts (16KB) per tile.
#define TILE_SH 8192
#define BSLAB   (FD*NN)          // shorts per batch slab (1 MB)

typedef __attribute__((ext_vector_type(8))) short short8;
typedef __attribute__((ext_vector_type(4))) float f32x4;
typedef __attribute__((ext_vector_type(4))) int   i32x4;

__device__ __forceinline__ unsigned short f2bf(float f){
  unsigned u = __builtin_bit_cast(unsigned, f);
  return (unsigned short)((u + 0x7FFFu + ((u>>16)&1u)) >> 16);   // RTN-even
}
__device__ __forceinline__ float dot4(float4 a, float4 b){
  return a.x*b.x + a.y*b.y + a.z*b.z + a.w*b.w;
}

// ---------------------------------------------------------------------------
// K0: w_src = W @ a_src, w_dst = W @ a_dst (exact fp32), WT[o][k] = bf16(W[k][o])
// ---------------------------------------------------------------------------
__global__ __launch_bounds__(64) void prep_w(
    const float* __restrict__ W, const float* __restrict__ a,
    float* __restrict__ w_src, float* __restrict__ w_dst,
    unsigned short* __restrict__ WT)
{
  const int k = blockIdx.x;
  const int l = threadIdx.x;
  float4 wv = *(const float4*)(W + k*FD + l*4);
  float4 as = *(const float4*)(a + l*4);
  float4 ad = *(const float4*)(a + FD + l*4);
  float s = dot4(wv, as);
  float d = dot4(wv, ad);
#pragma unroll
  for (int m=1;m<64;m<<=1){ s += __shfl_xor(s, m); d += __shfl_xor(d, m); }
  if (l == 0){ w_src[k] = s; w_dst[k] = d; }
  WT[(l*4+0)*FD + k] = f2bf(wv.x);
  WT[(l*4+1)*FD + k] = f2bf(wv.y);
  WT[(l*4+2)*FD + k] = f2bf(wv.z);
  WT[(l*4+3)*FD + k] = f2bf(wv.w);
}

// ---------------------------------------------------------------------------
// K0b: e_src/e_dst fp32 per row; xb = bf16(x)
// ---------------------------------------------------------------------------
__global__ __launch_bounds__(256) void prep_x(
    const float* __restrict__ x,
    const float* __restrict__ w_src, const float* __restrict__ w_dst,
    unsigned short* __restrict__ xb,
    float* __restrict__ e_src, float* __restrict__ e_dst)
{
  const int row = blockIdx.x*4 + (threadIdx.x >> 6);
  const int l = threadIdx.x & 63;
  float4 xv = *(const float4*)(x + (size_t)row*FD + l*4);
  float4 ws = *(const float4*)(w_src + l*4);
  float4 wd = *(const float4*)(w_dst + l*4);
  float s = dot4(xv, ws);
  float d = dot4(xv, wd);
#pragma unroll
  for (int m=1;m<64;m<<=1){ s += __shfl_xor(s, m); d += __shfl_xor(d, m); }
  if (l == 0){ e_src[row] = s; e_dst[row] = d; }
  uint2 u;
  u.x = (unsigned)f2bf(xv.x) | ((unsigned)f2bf(xv.y)<<16);
  u.y = (unsigned)f2bf(xv.z) | ((unsigned)f2bf(xv.w)<<16);
  *(uint2*)(xb + (size_t)row*FD + l*4) = u;
}

// ---------------------------------------------------------------------------
// K1: h = x @ W, bf16 MFMA, fragment-linear tiled output hTt[b][t][o][mj].
// XCD-affine: b = blockIdx & 7, so the slab is first-touched in the L2 of the
// XCD that gat_fused will read it from.
// ---------------------------------------------------------------------------
__global__ __launch_bounds__(256) void gemm_h(
    const unsigned short* __restrict__ xb,
    const unsigned short* __restrict__ WT,
    unsigned short* __restrict__ hT)
{
  const int tid = threadIdx.x;
  const int w = tid >> 6, l = tid & 63;
  const int r16 = l & 15, g = l >> 4;
  const int b    = blockIdx.x & 7;
  const int tile = blockIdx.x >> 3;           // 0..127 within batch
  const int row0 = b*NN + tile*16;

  f32x4 acc[4];
#pragma unroll
  for (int c=0;c<4;c++) acc[c] = (f32x4){0.f,0.f,0.f,0.f};

  const unsigned short* xrow  = xb + (size_t)(row0 + r16)*FD + g*8;
  const unsigned short* wbase = WT + (size_t)(w*64 + r16)*FD + g*8;
#pragma unroll
  for (int s=0;s<8;s++){
    short8 afrag = __builtin_bit_cast(short8, *(const int4*)(xrow + s*32));
#pragma unroll
    for (int cl=0;cl<4;cl++){
      int4 bv = *(const int4*)(wbase + (size_t)cl*16*FD + s*32);
      acc[cl] = __builtin_amdgcn_mfma_f32_16x16x32_bf16(
                  afrag, __builtin_bit_cast(short8, bv), acc[cl], 0, 0, 0);
    }
  }
  const int t  = tile >> 1;                   // m-tile of 32
  const int mj = ((tile & 1) << 4) + g*4;     // 4 consecutive m's
  unsigned short* dst = hT + (size_t)b*BSLAB + (size_t)t*TILE_SH + mj;
#pragma unroll
  for (int cl=0;cl<4;cl++){
    const int o = w*64 + cl*16 + r16;
    uint2 u;
    u.x = (unsigned)f2bf(acc[cl][0]) | ((unsigned)f2bf(acc[cl][1])<<16);
    u.y = (unsigned)f2bf(acc[cl][2]) | ((unsigned)f2bf(acc[cl][3])<<16);
    *(uint2*)(dst + o*32) = u;
  }
}

// ---------------------------------------------------------------------------
// K2: fused scores + exp + PV + normalize + ELU.
// Grid 1024 = 8 XCD-affine batches x 128 n-tiles of 16 rows. 4 waves/block,
// m-split (wave q: m in [512q,512q+512), 16 steps of 32). No barriers/LDS in
// main loop. Per step, ISSUE ORDER pinned with sched_barrier: 16 B-frag loads
// first, then mkp, then adj(nt)/e prefetch, then MFMA -> the MFMA wait is
// vmcnt(4) and never drains the prefetches. adj non-temporal so the 134 MB
// stream doesn't evict the L2-resident 1 MB hT slab.
// launch_bounds(256,2): ~256 VGPR budget so all 16 B-frags stay in flight.
// ---------------------------------------------------------------------------
__global__ __launch_bounds__(256,2) void gat_fused(
    const int* __restrict__ adj,
    const float* __restrict__ e_src,
    const float* __restrict__ e_dst,
    const unsigned short* __restrict__ hT,
    float* __restrict__ out)
{
  __shared__ f32x4 red[8][3][64];                 // 24 KB
  __shared__ float rsum[4][16];

  const int tid = threadIdx.x;
  const int q   = tid >> 6;            // m-quarter
  const int l   = tid & 63;
  const int r16 = l & 15, g = l >> 4;
  const int b   = blockIdx.x & 7;      // XCD-affine batch
  const int n0  = (blockIdx.x >> 3) << 4;

  const int* adjR = adj + (size_t)(b*NN + n0 + r16)*NN + q*512 + g*8;
  const float* edB = e_dst + b*NN + q*512 + g*8;
  const unsigned short* hTB = hT + (size_t)b*BSLAB + (size_t)q*16*TILE_SH
                                 + r16*32 + g*8;
  const float es = e_src[b*NN + n0 + r16];

  f32x4 acc[16];
#pragma unroll
  for (int c=0;c<16;c++) acc[c] = (f32x4){0.f,0.f,0.f,0.f};
  float ps = 0.f;

  auto mkp = [&](i32x4 a0, i32x4 a1, float4 e0, float4 e1)->short8{
    int   ai[8] = {a0[0],a0[1],a0[2],a0[3],a1[0],a1[1],a1[2],a1[3]};
    float ev[8] = {e0.x,e0.y,e0.z,e0.w,e1.x,e1.y,e1.z,e1.w};
    unsigned pt[8];
#pragma unroll
    for (int j=0;j<8;j++){
      float s = es + ev[j];
      s = fmaxf(s, ALPHA*s);                       // leaky relu
      float p = __expf(s);
      p = (ai[j] > 0) ? p : 0.f;
      unsigned ub = __builtin_bit_cast(unsigned, p) & 0xFFFF0000u;
      ps += __builtin_bit_cast(float, ub);         // rowsum of truncated P
      pt[j] = ub;
    }
    union { short8 v; unsigned u[4]; } A;
#pragma unroll
    for (int j=0;j<4;j++) A.u[j] = pt[2*j+1] | (pt[2*j] >> 16);
    return A.v;
  };

  // one m-step: B-frags first, compute P, refill prefetch slots, MFMA.
  auto STEP = [&](int t, i32x4& a0, i32x4& a1, float4& e0, float4& e1){
    const unsigned short* hb = hTB + (size_t)t*TILE_SH;
    int4 bf[16];
#pragma unroll
    for (int c=0;c<16;c++) bf[c] = *(const int4*)(hb + c*512);
    __builtin_amdgcn_sched_barrier(0);
    short8 pa = mkp(a0,a1,e0,e1);                  // consume slots for step t
    const int tn = (t+2 < 16) ? t+2 : 0;           // refill for t+2 (tail: dummy)
    const i32x4* ap = (const i32x4*)(adjR + tn*32);
    a0 = __builtin_nontemporal_load(ap);
    a1 = __builtin_nontemporal_load(ap+1);
    const float* ep = edB + tn*32;
    e0 = *(const float4*)ep; e1 = *(const float4*)(ep+4);
    __builtin_amdgcn_sched_barrier(0);
#pragma unroll
    for (int c=0;c<16;c++)
      acc[c] = __builtin_amdgcn_mfma_f32_16x16x32_bf16(
                 pa, __builtin_bit_cast(short8, bf[c]), acc[c], 0, 0, 0);
  };

  i32x4 ajA0,ajA1,ajB0,ajB1;
  float4 eA0,eA1,eB0,eB1;
  {
    const i32x4* ap = (const i32x4*)adjR;
    ajA0 = __builtin_nontemporal_load(ap);
    ajA1 = __builtin_nontemporal_load(ap+1);
    const i32x4* bp = (const i32x4*)(adjR + 32);
    ajB0 = __builtin_nontemporal_load(bp);
    ajB1 = __builtin_nontemporal_load(bp+1);
    eA0 = *(const float4*)edB;        eA1 = *(const float4*)(edB+4);
    eB0 = *(const float4*)(edB+32);   eB1 = *(const float4*)(edB+36);
  }

  for (int t = 0; t < 16; t += 2){
    STEP(t,   ajA0,ajA1, eA0,eA1);
    STEP(t+1, ajB0,ajB1, eB0,eB1);
  }

  // ---- partial rowsum: full m-quarter sum for row r16, all lanes ----
  float rs = ps;
  rs += __shfl_xor(rs, 16);
  rs += __shfl_xor(rs, 32);
  if (l < 16) rsum[q][l] = rs;

  // ---- combine round 0: c in [0,8) ----
  if (q > 0){
#pragma unroll
    for (int c=0;c<8;c++) red[c][q-1][l] = acc[c];
  }
  __syncthreads();

  if (q == 0){
    float tot = rsum[0][r16] + rsum[1][r16] + rsum[2][r16] + rsum[3][r16];
    float inv_[4];
#pragma unroll
    for (int r=0;r<4;r++) inv_[r] = 1.0f / __shfl(tot, g*4 + r);
    float* outB = out + (size_t)(b*NN + n0)*FD;
#pragma unroll
    for (int c=0;c<8;c++){
      f32x4 v = acc[c] + red[c][0][l] + red[c][1][l] + red[c][2][l];
#pragma unroll
      for (int r=0;r<4;r++){
        float o = v[r] * inv_[r];
        o = o > 0.f ? o : (__expf(o) - 1.f);       // ELU
        __builtin_nontemporal_store(o, &outB[(size_t)(g*4 + r)*FD + c*16 + r16]);
      }
    }
  }
  __syncthreads();

  // ---- combine round 1: c in [8,16) ----
  if (q > 0){
#pragma unroll
    for (int c=0;c<8;c++) red[c][q-1][l] = acc[8+c];
  }
  __syncthreads();

  if (q == 0){
    float tot = rsum[0][r16] + rsum[1][r16] + rsum[2][r16] + rsum[3][r16];
    float inv_[4];
#pragma unroll
    for (int r=0;r<4;r++) inv_[r] = 1.0f / __shfl(tot, g*4 + r);
    float* outB = out + (size_t)(b*NN + n0)*FD;
#pragma unroll
    for (int c=0;c<8;c++){
      f32x4 v = acc[8+c] + red[c][0][l] + red[c][1][l] + red[c][2][l];
#pragma unroll
      for (int r=0;r<4;r++){
        float o = v[r] * inv_[r];
        o = o > 0.f ? o : (__expf(o) - 1.f);       // ELU
        __builtin_nontemporal_store(o, &outB[(size_t)(g*4 + r)*FD + (8+c)*16 + r16]);
      }
    }
  }
}

// ---------------------------------------------------------------------------
extern "C" void kernel_launch(void* const* d_in, const int* in_sizes, int n_in,
                              void* d_out, int out_size, void* d_ws, size_t ws_size,
                              hipStream_t stream)
{
  const float* x   = (const float*)d_in[0];
  const int*   adj = (const int*)  d_in[1];
  const float* W   = (const float*)d_in[2];
  const float* a   = (const float*)d_in[3];
  float* out = (float*)d_out;

  char* ws = (char*)d_ws;
  size_t off = 0;
  auto alloc = [&](size_t bytes)->char*{
    char* p = ws + off; off += (bytes + 255) & ~(size_t)255; return p;
  };
  unsigned short* WT    = (unsigned short*)alloc((size_t)FD*FD*2);
  float*          w_src = (float*)alloc(FD*4);
  float*          w_dst = (float*)alloc(FD*4);
  float*          e_src = (float*)alloc((size_t)BATCH*NN*4);
  float*          e_dst = (float*)alloc((size_t)BATCH*NN*4);
  unsigned short* xb    = (unsigned short*)alloc((size_t)BATCH*NN*FD*2);
  unsigned short* hT    = (unsigned short*)alloc((size_t)BATCH*NN*FD*2);

  prep_w   <<<FD,              64,  0, stream>>>(W, a, w_src, w_dst, WT);
  prep_x   <<<(BATCH*NN)/4,    256, 0, stream>>>(x, w_src, w_dst, xb, e_src, e_dst);
  gemm_h   <<<(BATCH*NN)/16,   256, 0, stream>>>(xb, WT, hT);
  gat_fused<<<(BATCH*NN)/16,   256, 0, stream>>>(adj, e_src, e_dst, hT, out);
}

// Round 8
// 99.398 us; speedup vs baseline: 2.0034x; 1.3210x over previous
//
#include <hip/hip_runtime.h>

#define ALPHA 0.2f
#define BATCH 8
#define NN    2048
#define FD    256
// hT layout: [b][t=m/32][o=0..255][mj=0..31], short. 8192 shorts (16KB) per tile.
#define TILE_SH 8192
#define BSLAB   (FD*NN)          // shorts per batch slab (1 MB)

typedef __attribute__((ext_vector_type(8))) short short8;
typedef __attribute__((ext_vector_type(4))) float f32x4;
typedef __attribute__((ext_vector_type(4))) int   i32x4;

__device__ __forceinline__ unsigned short f2bf(float f){
  unsigned u = __builtin_bit_cast(unsigned, f);
  return (unsigned short)((u + 0x7FFFu + ((u>>16)&1u)) >> 16);   // RTN-even
}
__device__ __forceinline__ float dot4(float4 a, float4 b){
  return a.x*b.x + a.y*b.y + a.z*b.z + a.w*b.w;
}

// ---------------------------------------------------------------------------
// K0: w_src = W @ a_src, w_dst = W @ a_dst (exact fp32), WT[o][k] = bf16(W[k][o])
// ---------------------------------------------------------------------------
__global__ __launch_bounds__(64) void prep_w(
    const float* __restrict__ W, const float* __restrict__ a,
    float* __restrict__ w_src, float* __restrict__ w_dst,
    unsigned short* __restrict__ WT)
{
  const int k = blockIdx.x;
  const int l = threadIdx.x;
  float4 wv = *(const float4*)(W + k*FD + l*4);
  float4 as = *(const float4*)(a + l*4);
  float4 ad = *(const float4*)(a + FD + l*4);
  float s = dot4(wv, as);
  float d = dot4(wv, ad);
#pragma unroll
  for (int m=1;m<64;m<<=1){ s += __shfl_xor(s, m); d += __shfl_xor(d, m); }
  if (l == 0){ w_src[k] = s; w_dst[k] = d; }
  WT[(l*4+0)*FD + k] = f2bf(wv.x);
  WT[(l*4+1)*FD + k] = f2bf(wv.y);
  WT[(l*4+2)*FD + k] = f2bf(wv.z);
  WT[(l*4+3)*FD + k] = f2bf(wv.w);
}

// ---------------------------------------------------------------------------
// K0b: e_src/e_dst fp32 per row; xb = bf16(x)
// ---------------------------------------------------------------------------
__global__ __launch_bounds__(256) void prep_x(
    const float* __restrict__ x,
    const float* __restrict__ w_src, const float* __restrict__ w_dst,
    unsigned short* __restrict__ xb,
    float* __restrict__ e_src, float* __restrict__ e_dst)
{
  const int row = blockIdx.x*4 + (threadIdx.x >> 6);
  const int l = threadIdx.x & 63;
  float4 xv = *(const float4*)(x + (size_t)row*FD + l*4);
  float4 ws = *(const float4*)(w_src + l*4);
  float4 wd = *(const float4*)(w_dst + l*4);
  float s = dot4(xv, ws);
  float d = dot4(xv, wd);
#pragma unroll
  for (int m=1;m<64;m<<=1){ s += __shfl_xor(s, m); d += __shfl_xor(d, m); }
  if (l == 0){ e_src[row] = s; e_dst[row] = d; }
  uint2 u;
  u.x = (unsigned)f2bf(xv.x) | ((unsigned)f2bf(xv.y)<<16);
  u.y = (unsigned)f2bf(xv.z) | ((unsigned)f2bf(xv.w)<<16);
  *(uint2*)(xb + (size_t)row*FD + l*4) = u;
}

// ---------------------------------------------------------------------------
// K1: h = x @ W, bf16 MFMA, fragment-linear tiled output hTt[b][t][o][mj].
// XCD-affine: b = blockIdx & 7.
// ---------------------------------------------------------------------------
__global__ __launch_bounds__(256) void gemm_h(
    const unsigned short* __restrict__ xb,
    const unsigned short* __restrict__ WT,
    unsigned short* __restrict__ hT)
{
  const int tid = threadIdx.x;
  const int w = tid >> 6, l = tid & 63;
  const int r16 = l & 15, g = l >> 4;
  const int b    = blockIdx.x & 7;
  const int tile = blockIdx.x >> 3;           // 0..127 within batch
  const int row0 = b*NN + tile*16;

  f32x4 acc[4];
#pragma unroll
  for (int c=0;c<4;c++) acc[c] = (f32x4){0.f,0.f,0.f,0.f};

  const unsigned short* xrow  = xb + (size_t)(row0 + r16)*FD + g*8;
  const unsigned short* wbase = WT + (size_t)(w*64 + r16)*FD + g*8;
#pragma unroll
  for (int s=0;s<8;s++){
    short8 afrag = __builtin_bit_cast(short8, *(const int4*)(xrow + s*32));
#pragma unroll
    for (int cl=0;cl<4;cl++){
      int4 bv = *(const int4*)(wbase + (size_t)cl*16*FD + s*32);
      acc[cl] = __builtin_amdgcn_mfma_f32_16x16x32_bf16(
                  afrag, __builtin_bit_cast(short8, bv), acc[cl], 0, 0, 0);
    }
  }
  const int t  = tile >> 1;                   // m-tile of 32
  const int mj = ((tile & 1) << 4) + g*4;     // 4 consecutive m's
  unsigned short* dst = hT + (size_t)b*BSLAB + (size_t)t*TILE_SH + mj;
#pragma unroll
  for (int cl=0;cl<4;cl++){
    const int o = w*64 + cl*16 + r16;
    uint2 u;
    u.x = (unsigned)f2bf(acc[cl][0]) | ((unsigned)f2bf(acc[cl][1])<<16);
    u.y = (unsigned)f2bf(acc[cl][2]) | ((unsigned)f2bf(acc[cl][3])<<16);
    *(uint2*)(dst + o*32) = u;
  }
}

// ---------------------------------------------------------------------------
// K2: fused scores + exp + PV + normalize + ELU.
// Grid 512 = 8 XCD-affine batches x 64 n-tiles of 32 rows. 4 waves/block,
// m-split (wave q: m in [512q,512q+512), 16 steps of 32). Each wave computes
// TWO 16-row n-tiles against the SAME 16 B-frag loads (2x arithmetic
// intensity; hT traffic 1GB -> 512MB). Issue order per step: e (L1-hot, so
// mkp's wait leaves bf in flight), then 16 bf loads, mkp x2, adj(nt) refill
// (after mkp -> MFMA's wait leaves adj in flight), then 32 MFMA.
// Epilogue: 4 LDS rounds (2 tiles x 2 acc-halves), all waves finalize.
// ---------------------------------------------------------------------------
__global__ __launch_bounds__(256,2) void gat_fused(
    const int* __restrict__ adj,
    const float* __restrict__ e_src,
    const float* __restrict__ e_dst,
    const unsigned short* __restrict__ hT,
    float* __restrict__ out)
{
  __shared__ f32x4 red[8][4][64];                 // 32 KB
  __shared__ float rsum[2][4][16];

  const int tid = threadIdx.x;
  const int q   = tid >> 6;            // m-quarter
  const int l   = tid & 63;
  const int r16 = l & 15, g = l >> 4;
  const int b   = blockIdx.x & 7;      // XCD-affine batch
  const int n0  = (blockIdx.x >> 3) << 5;        // 32 rows/block

  const int* adjR0 = adj + (size_t)(b*NN + n0 + r16)*NN + q*512 + g*8;
  const int* adjR1 = adjR0 + (size_t)16*NN;
  const float* edB = e_dst + b*NN + q*512 + g*8;
  const unsigned short* hTB = hT + (size_t)b*BSLAB + (size_t)q*16*TILE_SH
                                 + r16*32 + g*8;
  const float es0 = e_src[b*NN + n0 + r16];
  const float es1 = e_src[b*NN + n0 + 16 + r16];

  f32x4 acc0[16], acc1[16];
#pragma unroll
  for (int c=0;c<16;c++){ acc0[c] = (f32x4){0.f,0.f,0.f,0.f};
                          acc1[c] = (f32x4){0.f,0.f,0.f,0.f}; }
  float ps0 = 0.f, ps1 = 0.f;

  auto mkp = [&](i32x4 a0, i32x4 a1, float4 e0, float4 e1,
                 float es, float& ps)->short8{
    int   ai[8] = {a0[0],a0[1],a0[2],a0[3],a1[0],a1[1],a1[2],a1[3]};
    float ev[8] = {e0.x,e0.y,e0.z,e0.w,e1.x,e1.y,e1.z,e1.w};
    unsigned pt[8];
#pragma unroll
    for (int j=0;j<8;j++){
      float s = es + ev[j];
      s = fmaxf(s, ALPHA*s);                       // leaky relu
      float p = __expf(s);
      p = (ai[j] > 0) ? p : 0.f;
      unsigned ub = __builtin_bit_cast(unsigned, p) & 0xFFFF0000u;
      ps += __builtin_bit_cast(float, ub);         // rowsum of truncated P
      pt[j] = ub;
    }
    union { short8 v; unsigned u[4]; } A;
#pragma unroll
    for (int j=0;j<4;j++) A.u[j] = pt[2*j+1] | (pt[2*j] >> 16);
    return A.v;
  };

  i32x4 aj00,aj01, aj10,aj11;
  {
    const i32x4* p0 = (const i32x4*)adjR0;
    aj00 = __builtin_nontemporal_load(p0);
    aj01 = __builtin_nontemporal_load(p0+1);
    const i32x4* p1 = (const i32x4*)adjR1;
    aj10 = __builtin_nontemporal_load(p1);
    aj11 = __builtin_nontemporal_load(p1+1);
  }

  for (int t = 0; t < 16; ++t){
    // e first (L1-hot): mkp's vm-wait leaves the 16 bf loads in flight
    const float* ep = edB + t*32;
    float4 e0 = *(const float4*)ep, e1 = *(const float4*)(ep+4);
    const unsigned short* hb = hTB + (size_t)t*TILE_SH;
    int4 bf[16];
#pragma unroll
    for (int c=0;c<16;c++) bf[c] = *(const int4*)(hb + c*512);
    __builtin_amdgcn_sched_barrier(0);
    short8 pa0 = mkp(aj00,aj01, e0,e1, es0, ps0);
    short8 pa1 = mkp(aj10,aj11, e0,e1, es1, ps1);
    const int tn = (t+1 < 16) ? t+1 : 0;           // depth-1 refill (tail dummy)
    {
      const i32x4* p0 = (const i32x4*)(adjR0 + tn*32);
      aj00 = __builtin_nontemporal_load(p0);
      aj01 = __builtin_nontemporal_load(p0+1);
      const i32x4* p1 = (const i32x4*)(adjR1 + tn*32);
      aj10 = __builtin_nontemporal_load(p1);
      aj11 = __builtin_nontemporal_load(p1+1);
    }
    __builtin_amdgcn_sched_barrier(0);
#pragma unroll
    for (int c=0;c<16;c++)
      acc0[c] = __builtin_amdgcn_mfma_f32_16x16x32_bf16(
                  pa0, __builtin_bit_cast(short8, bf[c]), acc0[c], 0, 0, 0);
#pragma unroll
    for (int c=0;c<16;c++)
      acc1[c] = __builtin_amdgcn_mfma_f32_16x16x32_bf16(
                  pa1, __builtin_bit_cast(short8, bf[c]), acc1[c], 0, 0, 0);
  }

  // ---- partial rowsums ----
  float rs0 = ps0, rs1 = ps1;
  rs0 += __shfl_xor(rs0, 16); rs0 += __shfl_xor(rs0, 32);
  rs1 += __shfl_xor(rs1, 16); rs1 += __shfl_xor(rs1, 32);
  if (l < 16){ rsum[0][q][l] = rs0; rsum[1][q][l] = rs1; }

  // ---- 4 combine rounds: (tile, acc-half) ----
  float inv0[4], inv1[4];
  float* outB0 = out + (size_t)(b*NN + n0)*FD;
  float* outB1 = outB0 + (size_t)16*FD;

#pragma unroll
  for (int rd = 0; rd < 4; ++rd){
    const int tile = rd >> 1, h = rd & 1;
    f32x4* accp = tile ? acc1 : acc0;
#pragma unroll
    for (int c=0;c<8;c++) red[c][q][l] = accp[h*8+c];
    __syncthreads();
    if (rd == 0){
      float t0 = rsum[0][0][r16] + rsum[0][1][r16] + rsum[0][2][r16] + rsum[0][3][r16];
      float t1 = rsum[1][0][r16] + rsum[1][1][r16] + rsum[1][2][r16] + rsum[1][3][r16];
#pragma unroll
      for (int r=0;r<4;r++){ inv0[r] = 1.0f / __shfl(t0, g*4 + r);
                             inv1[r] = 1.0f / __shfl(t1, g*4 + r); }
    }
    const float* inv_ = tile ? inv1 : inv0;
    float* outB = tile ? outB1 : outB0;
#pragma unroll
    for (int i=0;i<2;i++){
      const int c = q*2 + i;
      f32x4 v = red[c][0][l] + red[c][1][l] + red[c][2][l] + red[c][3][l];
#pragma unroll
      for (int r=0;r<4;r++){
        float o = v[r] * inv_[r];
        o = o > 0.f ? o : (__expf(o) - 1.f);       // ELU
        __builtin_nontemporal_store(o,
            &outB[(size_t)(g*4 + r)*FD + (h*8 + c)*16 + r16]);
      }
    }
    __syncthreads();
  }
}

// ---------------------------------------------------------------------------
extern "C" void kernel_launch(void* const* d_in, const int* in_sizes, int n_in,
                              void* d_out, int out_size, void* d_ws, size_t ws_size,
                              hipStream_t stream)
{
  const float* x   = (const float*)d_in[0];
  const int*   adj = (const int*)  d_in[1];
  const float* W   = (const float*)d_in[2];
  const float* a   = (const float*)d_in[3];
  float* out = (float*)d_out;

  char* ws = (char*)d_ws;
  size_t off = 0;
  auto alloc = [&](size_t bytes)->char*{
    char* p = ws + off; off += (bytes + 255) & ~(size_t)255; return p;
  };
  unsigned short* WT    = (unsigned short*)alloc((size_t)FD*FD*2);
  float*          w_src = (float*)alloc(FD*4);
  float*          w_dst = (float*)alloc(FD*4);
  float*          e_src = (float*)alloc((size_t)BATCH*NN*4);
  float*          e_dst = (float*)alloc((size_t)BATCH*NN*4);
  unsigned short* xb    = (unsigned short*)alloc((size_t)BATCH*NN*FD*2);
  unsigned short* hT    = (unsigned short*)alloc((size_t)BATCH*NN*FD*2);

  prep_w   <<<FD,              64,  0, stream>>>(W, a, w_src, w_dst, WT);
  prep_x   <<<(BATCH*NN)/4,    256, 0, stream>>>(x, w_src, w_dst, xb, e_src, e_dst);
  gemm_h   <<<(BATCH*NN)/16,   256, 0, stream>>>(xb, WT, hT);
  gat_fused<<<(BATCH*NN)/32,   256, 0, stream>>>(adj, e_src, e_dst, hT, out);
}

// Round 9
// 92.519 us; speedup vs baseline: 2.1524x; 1.0744x over previous
//
#include <hip/hip_runtime.h>

#define ALPHA 0.2f
#define BATCH 8
#define NN    2048
#define FD    256
// hT layout: [b][t=m/32][o=0..255][mj=0..31], short. 8192 shorts (16KB) per tile.
#define TILE_SH 8192
#define BSLAB   (FD*NN)          // shorts per batch slab (1 MB)

typedef __attribute__((ext_vector_type(8))) short short8;
typedef __attribute__((ext_vector_type(4))) float f32x4;
typedef __attribute__((ext_vector_type(4))) int   i32x4;

__device__ __forceinline__ unsigned short f2bf(float f){
  unsigned u = __builtin_bit_cast(unsigned, f);
  return (unsigned short)((u + 0x7FFFu + ((u>>16)&1u)) >> 16);   // RTN-even
}
__device__ __forceinline__ float dot4(float4 a, float4 b){
  return a.x*b.x + a.y*b.y + a.z*b.z + a.w*b.w;
}

// ---------------------------------------------------------------------------
// K0: w_src = W @ a_src, w_dst = W @ a_dst (exact fp32), WT[o][k] = bf16(W[k][o])
// ---------------------------------------------------------------------------
__global__ __launch_bounds__(64) void prep_w(
    const float* __restrict__ W, const float* __restrict__ a,
    float* __restrict__ w_src, float* __restrict__ w_dst,
    unsigned short* __restrict__ WT)
{
  const int k = blockIdx.x;
  const int l = threadIdx.x;
  float4 wv = *(const float4*)(W + k*FD + l*4);
  float4 as = *(const float4*)(a + l*4);
  float4 ad = *(const float4*)(a + FD + l*4);
  float s = dot4(wv, as);
  float d = dot4(wv, ad);
#pragma unroll
  for (int m=1;m<64;m<<=1){ s += __shfl_xor(s, m); d += __shfl_xor(d, m); }
  if (l == 0){ w_src[k] = s; w_dst[k] = d; }
  WT[(l*4+0)*FD + k] = f2bf(wv.x);
  WT[(l*4+1)*FD + k] = f2bf(wv.y);
  WT[(l*4+2)*FD + k] = f2bf(wv.z);
  WT[(l*4+3)*FD + k] = f2bf(wv.w);
}

// ---------------------------------------------------------------------------
// K0b: e_src/e_dst fp32 per row; xb = bf16(x)
// ---------------------------------------------------------------------------
__global__ __launch_bounds__(256) void prep_x(
    const float* __restrict__ x,
    const float* __restrict__ w_src, const float* __restrict__ w_dst,
    unsigned short* __restrict__ xb,
    float* __restrict__ e_src, float* __restrict__ e_dst)
{
  const int row = blockIdx.x*4 + (threadIdx.x >> 6);
  const int l = threadIdx.x & 63;
  float4 xv = *(const float4*)(x + (size_t)row*FD + l*4);
  float4 ws = *(const float4*)(w_src + l*4);
  float4 wd = *(const float4*)(w_dst + l*4);
  float s = dot4(xv, ws);
  float d = dot4(xv, wd);
#pragma unroll
  for (int m=1;m<64;m<<=1){ s += __shfl_xor(s, m); d += __shfl_xor(d, m); }
  if (l == 0){ e_src[row] = s; e_dst[row] = d; }
  uint2 u;
  u.x = (unsigned)f2bf(xv.x) | ((unsigned)f2bf(xv.y)<<16);
  u.y = (unsigned)f2bf(xv.z) | ((unsigned)f2bf(xv.w)<<16);
  *(uint2*)(xb + (size_t)row*FD + l*4) = u;
}

// ---------------------------------------------------------------------------
// K1: h = x @ W, bf16 MFMA, fragment-linear tiled output hTt[b][t][o][mj].
// 64-row XCD-affine blocks (grid 256): WT read ONCE per block (B in regs,
// s-outer loop), A-frags shared across the 4 c-split waves via L1.
// ---------------------------------------------------------------------------
__global__ __launch_bounds__(256) void gemm_h(
    const unsigned short* __restrict__ xb,
    const unsigned short* __restrict__ WT,
    unsigned short* __restrict__ hT)
{
  const int tid = threadIdx.x;
  const int w = tid >> 6, l = tid & 63;
  const int r16 = l & 15, g = l >> 4;
  const int b  = blockIdx.x & 7;
  const int nl = (blockIdx.x >> 3) << 6;      // 64 local rows
  const int row0 = b*NN + nl;

  f32x4 acc[4][4];                            // [row-group][cl]
#pragma unroll
  for (int gp=0;gp<4;gp++)
#pragma unroll
    for (int c=0;c<4;c++) acc[gp][c] = (f32x4){0.f,0.f,0.f,0.f};

  const unsigned short* xbase = xb + (size_t)(row0 + r16)*FD + g*8;
  const unsigned short* wbase = WT + (size_t)(w*64 + r16)*FD + g*8;
#pragma unroll
  for (int s=0;s<8;s++){
    int4 bfr[4];
#pragma unroll
    for (int cl=0;cl<4;cl++)
      bfr[cl] = *(const int4*)(wbase + (size_t)cl*16*FD + s*32);
#pragma unroll
    for (int gp=0;gp<4;gp++){
      short8 afrag = __builtin_bit_cast(short8,
          *(const int4*)(xbase + (size_t)gp*16*FD + s*32));
#pragma unroll
      for (int cl=0;cl<4;cl++)
        acc[gp][cl] = __builtin_amdgcn_mfma_f32_16x16x32_bf16(
            afrag, __builtin_bit_cast(short8, bfr[cl]), acc[gp][cl], 0, 0, 0);
    }
  }
#pragma unroll
  for (int gp=0;gp<4;gp++){
    const int rl  = nl + gp*16;               // local row base
    const int t   = rl >> 5;                  // m-tile of 32
    const int mj  = ((rl >> 4) & 1) * 16 + g*4;
    unsigned short* dst = hT + (size_t)b*BSLAB + (size_t)t*TILE_SH + mj;
#pragma unroll
    for (int cl=0;cl<4;cl++){
      const int o = w*64 + cl*16 + r16;
      uint2 u;
      u.x = (unsigned)f2bf(acc[gp][cl][0]) | ((unsigned)f2bf(acc[gp][cl][1])<<16);
      u.y = (unsigned)f2bf(acc[gp][cl][2]) | ((unsigned)f2bf(acc[gp][cl][3])<<16);
      *(uint2*)(dst + o*32) = u;
    }
  }
}

// ---------------------------------------------------------------------------
// K2: fused scores + exp + PV + normalize + ELU.
// Grid 256 = 8 XCD-affine batches x 32 n-tiles of 64 rows. 512 threads =
// 8 waves = 4 m-quarters (q) x 2 n-pairs (w). Wave (q,w): rows n0+w*32+{0,16},
// m in [512q,512q+512), 16 steps of 32; 16 B-frag loads feed 32 MFMA (2x
// intensity), and the (q,0)/(q,1) pair reads IDENTICAL B-frag addresses ->
// L1 reuse halves L2-port traffic. hT chip traffic 256 MB. No main-loop
// barriers; adj nt-prefetch depth 1. Epilogue: 64 KB LDS, 4 rounds, both
// w-groups in parallel.
// ---------------------------------------------------------------------------
__global__ __launch_bounds__(512,2) void gat_fused(
    const int* __restrict__ adj,
    const float* __restrict__ e_src,
    const float* __restrict__ e_dst,
    const unsigned short* __restrict__ hT,
    float* __restrict__ out)
{
  __shared__ f32x4 red[2][8][4][64];              // 64 KB [w][c][q][l]
  __shared__ float rsum[4][4][16];                // [tile][q][16]

  const int tid = threadIdx.x;
  const int Wv  = tid >> 6;
  const int q   = Wv & 3;              // m-quarter
  const int w   = Wv >> 2;             // n-pair
  const int l   = tid & 63;
  const int r16 = l & 15, g = l >> 4;
  const int b   = blockIdx.x & 7;      // XCD-affine batch
  const int n0  = (blockIdx.x >> 3) << 6;        // 64 rows/block

  const int* adjR0 = adj + (size_t)(b*NN + n0 + w*32 + r16)*NN + q*512 + g*8;
  const int* adjR1 = adjR0 + (size_t)16*NN;
  const float* edB = e_dst + b*NN + q*512 + g*8;
  const unsigned short* hTB = hT + (size_t)b*BSLAB + (size_t)q*16*TILE_SH
                                 + r16*32 + g*8;
  const float es0 = e_src[b*NN + n0 + w*32 + r16];
  const float es1 = e_src[b*NN + n0 + w*32 + 16 + r16];

  f32x4 acc0[16], acc1[16];
#pragma unroll
  for (int c=0;c<16;c++){ acc0[c] = (f32x4){0.f,0.f,0.f,0.f};
                          acc1[c] = (f32x4){0.f,0.f,0.f,0.f}; }
  float ps0 = 0.f, ps1 = 0.f;

  auto mkp = [&](i32x4 a0, i32x4 a1, float4 e0, float4 e1,
                 float es, float& ps)->short8{
    int   ai[8] = {a0[0],a0[1],a0[2],a0[3],a1[0],a1[1],a1[2],a1[3]};
    float ev[8] = {e0.x,e0.y,e0.z,e0.w,e1.x,e1.y,e1.z,e1.w};
    unsigned pt[8];
#pragma unroll
    for (int j=0;j<8;j++){
      float s = es + ev[j];
      s = fmaxf(s, ALPHA*s);                       // leaky relu
      float p = __expf(s);
      p = (ai[j] > 0) ? p : 0.f;
      unsigned ub = __builtin_bit_cast(unsigned, p) & 0xFFFF0000u;
      ps += __builtin_bit_cast(float, ub);         // rowsum of truncated P
      pt[j] = ub;
    }
    union { short8 v; unsigned u[4]; } A;
#pragma unroll
    for (int j=0;j<4;j++) A.u[j] = pt[2*j+1] | (pt[2*j] >> 16);
    return A.v;
  };

  i32x4 aj00,aj01, aj10,aj11;
  {
    const i32x4* p0 = (const i32x4*)adjR0;
    aj00 = __builtin_nontemporal_load(p0);
    aj01 = __builtin_nontemporal_load(p0+1);
    const i32x4* p1 = (const i32x4*)adjR1;
    aj10 = __builtin_nontemporal_load(p1);
    aj11 = __builtin_nontemporal_load(p1+1);
  }

  for (int t = 0; t < 16; ++t){
    // e first (L1-hot): mkp's vm-wait leaves the 16 bf loads in flight
    const float* ep = edB + t*32;
    float4 e0 = *(const float4*)ep, e1 = *(const float4*)(ep+4);
    const unsigned short* hb = hTB + (size_t)t*TILE_SH;
    int4 bf[16];
#pragma unroll
    for (int c=0;c<16;c++) bf[c] = *(const int4*)(hb + c*512);
    __builtin_amdgcn_sched_barrier(0);
    short8 pa0 = mkp(aj00,aj01, e0,e1, es0, ps0);
    short8 pa1 = mkp(aj10,aj11, e0,e1, es1, ps1);
    const int tn = (t+1 < 16) ? t+1 : 0;           // depth-1 refill (tail dummy)
    {
      const i32x4* p0 = (const i32x4*)(adjR0 + tn*32);
      aj00 = __builtin_nontemporal_load(p0);
      aj01 = __builtin_nontemporal_load(p0+1);
      const i32x4* p1 = (const i32x4*)(adjR1 + tn*32);
      aj10 = __builtin_nontemporal_load(p1);
      aj11 = __builtin_nontemporal_load(p1+1);
    }
    __builtin_amdgcn_sched_barrier(0);
#pragma unroll
    for (int c=0;c<16;c++)
      acc0[c] = __builtin_amdgcn_mfma_f32_16x16x32_bf16(
                  pa0, __builtin_bit_cast(short8, bf[c]), acc0[c], 0, 0, 0);
#pragma unroll
    for (int c=0;c<16;c++)
      acc1[c] = __builtin_amdgcn_mfma_f32_16x16x32_bf16(
                  pa1, __builtin_bit_cast(short8, bf[c]), acc1[c], 0, 0, 0);
  }

  // ---- partial rowsums ----
  float rs0 = ps0, rs1 = ps1;
  rs0 += __shfl_xor(rs0, 16); rs0 += __shfl_xor(rs0, 32);
  rs1 += __shfl_xor(rs1, 16); rs1 += __shfl_xor(rs1, 32);
  if (l < 16){ rsum[w*2][q][l] = rs0; rsum[w*2+1][q][l] = rs1; }
  __syncthreads();

  // tile totals + inv for this wave's two tiles
  float t0 = rsum[w*2  ][0][r16] + rsum[w*2  ][1][r16]
           + rsum[w*2  ][2][r16] + rsum[w*2  ][3][r16];
  float t1 = rsum[w*2+1][0][r16] + rsum[w*2+1][1][r16]
           + rsum[w*2+1][2][r16] + rsum[w*2+1][3][r16];
  float inv0[4], inv1[4];
#pragma unroll
  for (int r=0;r<4;r++){ inv0[r] = 1.0f / __shfl(t0, g*4 + r);
                         inv1[r] = 1.0f / __shfl(t1, g*4 + r); }

  // ---- 4 combine rounds: (pair-slot s, acc-half h); w-groups in parallel ----
#pragma unroll
  for (int rd = 0; rd < 4; ++rd){
    const int s = rd >> 1, h = rd & 1;
    f32x4* accp = s ? acc1 : acc0;
#pragma unroll
    for (int c=0;c<8;c++) red[w][c][q][l] = accp[h*8+c];
    __syncthreads();
    const float* inv_ = s ? inv1 : inv0;
    float* outB = out + (size_t)(b*NN + n0 + w*32 + s*16)*FD;
#pragma unroll
    for (int i=0;i<2;i++){
      const int c = q*2 + i;
      f32x4 v = red[w][c][0][l] + red[w][c][1][l]
              + red[w][c][2][l] + red[w][c][3][l];
#pragma unroll
      for (int r=0;r<4;r++){
        float o = v[r] * inv_[r];
        o = o > 0.f ? o : (__expf(o) - 1.f);       // ELU
        __builtin_nontemporal_store(o,
            &outB[(size_t)(g*4 + r)*FD + (h*8 + c)*16 + r16]);
      }
    }
    __syncthreads();
  }
}

// ---------------------------------------------------------------------------
extern "C" void kernel_launch(void* const* d_in, const int* in_sizes, int n_in,
                              void* d_out, int out_size, void* d_ws, size_t ws_size,
                              hipStream_t stream)
{
  const float* x   = (const float*)d_in[0];
  const int*   adj = (const int*)  d_in[1];
  const float* W   = (const float*)d_in[2];
  const float* a   = (const float*)d_in[3];
  float* out = (float*)d_out;

  char* ws = (char*)d_ws;
  size_t off = 0;
  auto alloc = [&](size_t bytes)->char*{
    char* p = ws + off; off += (bytes + 255) & ~(size_t)255; return p;
  };
  unsigned short* WT    = (unsigned short*)alloc((size_t)FD*FD*2);
  float*          w_src = (float*)alloc(FD*4);
  float*          w_dst = (float*)alloc(FD*4);
  float*          e_src = (float*)alloc((size_t)BATCH*NN*4);
  float*          e_dst = (float*)alloc((size_t)BATCH*NN*4);
  unsigned short* xb    = (unsigned short*)alloc((size_t)BATCH*NN*FD*2);
  unsigned short* hT    = (unsigned short*)alloc((size_t)BATCH*NN*FD*2);

  prep_w   <<<FD,              64,  0, stream>>>(W, a, w_src, w_dst, WT);
  prep_x   <<<(BATCH*NN)/4,    256, 0, stream>>>(x, w_src, w_dst, xb, e_src, e_dst);
  gemm_h   <<<(BATCH*NN)/64,   256, 0, stream>>>(xb, WT, hT);
  gat_fused<<<(BATCH*NN)/64,   512, 0, stream>>>(adj, e_src, e_dst, hT, out);
}

// Round 10
// 81.285 us; speedup vs baseline: 2.4498x; 1.1382x over previous
//
#include <hip/hip_runtime.h>

#define ALPHA 0.2f
#define BATCH 8
#define NN    2048
#define FD    256
// hT layout: [b][t=m/32][o=0..255][mj=0..31], short. 8192 shorts (16KB) per tile.
#define TILE_SH 8192
#define BSLAB   (FD*NN)          // shorts per batch slab (1 MB)

typedef __attribute__((ext_vector_type(8))) short short8;
typedef __attribute__((ext_vector_type(4))) float f32x4;
typedef __attribute__((ext_vector_type(4))) int   i32x4;

__device__ __forceinline__ unsigned short f2bf(float f){
  unsigned u = __builtin_bit_cast(unsigned, f);
  return (unsigned short)((u + 0x7FFFu + ((u>>16)&1u)) >> 16);   // RTN-even
}
__device__ __forceinline__ float dot4(float4 a, float4 b){
  return a.x*b.x + a.y*b.y + a.z*b.z + a.w*b.w;
}
// async global->LDS, 16B/lane: dest = uniform base + lane*16; src is per-lane.
__device__ __forceinline__ void gll16(const void* g, void* l){
  __builtin_amdgcn_global_load_lds(
      (const __attribute__((address_space(1))) unsigned int*)g,
      (__attribute__((address_space(3))) unsigned int*)l, 16, 0, 0);
}

// ---------------------------------------------------------------------------
// K0: w_src = W @ a_src, w_dst = W @ a_dst (exact fp32), WT[o][k] = bf16(W[k][o])
// ---------------------------------------------------------------------------
__global__ __launch_bounds__(64) void prep_w(
    const float* __restrict__ W, const float* __restrict__ a,
    float* __restrict__ w_src, float* __restrict__ w_dst,
    unsigned short* __restrict__ WT)
{
  const int k = blockIdx.x;
  const int l = threadIdx.x;
  float4 wv = *(const float4*)(W + k*FD + l*4);
  float4 as = *(const float4*)(a + l*4);
  float4 ad = *(const float4*)(a + FD + l*4);
  float s = dot4(wv, as);
  float d = dot4(wv, ad);
#pragma unroll
  for (int m=1;m<64;m<<=1){ s += __shfl_xor(s, m); d += __shfl_xor(d, m); }
  if (l == 0){ w_src[k] = s; w_dst[k] = d; }
  WT[(l*4+0)*FD + k] = f2bf(wv.x);
  WT[(l*4+1)*FD + k] = f2bf(wv.y);
  WT[(l*4+2)*FD + k] = f2bf(wv.z);
  WT[(l*4+3)*FD + k] = f2bf(wv.w);
}

// ---------------------------------------------------------------------------
// K0b: e_src/e_dst fp32 per row; xb = bf16(x)
// ---------------------------------------------------------------------------
__global__ __launch_bounds__(256) void prep_x(
    const float* __restrict__ x,
    const float* __restrict__ w_src, const float* __restrict__ w_dst,
    unsigned short* __restrict__ xb,
    float* __restrict__ e_src, float* __restrict__ e_dst)
{
  const int row = blockIdx.x*4 + (threadIdx.x >> 6);
  const int l = threadIdx.x & 63;
  float4 xv = *(const float4*)(x + (size_t)row*FD + l*4);
  float4 ws = *(const float4*)(w_src + l*4);
  float4 wd = *(const float4*)(w_dst + l*4);
  float s = dot4(xv, ws);
  float d = dot4(xv, wd);
#pragma unroll
  for (int m=1;m<64;m<<=1){ s += __shfl_xor(s, m); d += __shfl_xor(d, m); }
  if (l == 0){ e_src[row] = s; e_dst[row] = d; }
  uint2 u;
  u.x = (unsigned)f2bf(xv.x) | ((unsigned)f2bf(xv.y)<<16);
  u.y = (unsigned)f2bf(xv.z) | ((unsigned)f2bf(xv.w)<<16);
  *(uint2*)(xb + (size_t)row*FD + l*4) = u;
}

// ---------------------------------------------------------------------------
// K1: h = x @ W, bf16 MFMA, fragment-linear tiled output hTt[b][t][o][mj].
// 64-row XCD-affine blocks (grid 256): WT read once per block, A shared via L1.
// ---------------------------------------------------------------------------
__global__ __launch_bounds__(256) void gemm_h(
    const unsigned short* __restrict__ xb,
    const unsigned short* __restrict__ WT,
    unsigned short* __restrict__ hT)
{
  const int tid = threadIdx.x;
  const int w = tid >> 6, l = tid & 63;
  const int r16 = l & 15, g = l >> 4;
  const int b  = blockIdx.x & 7;
  const int nl = (blockIdx.x >> 3) << 6;      // 64 local rows
  const int row0 = b*NN + nl;

  f32x4 acc[4][4];                            // [row-group][cl]
#pragma unroll
  for (int gp=0;gp<4;gp++)
#pragma unroll
    for (int c=0;c<4;c++) acc[gp][c] = (f32x4){0.f,0.f,0.f,0.f};

  const unsigned short* xbase = xb + (size_t)(row0 + r16)*FD + g*8;
  const unsigned short* wbase = WT + (size_t)(w*64 + r16)*FD + g*8;
#pragma unroll
  for (int s=0;s<8;s++){
    int4 bfr[4];
#pragma unroll
    for (int cl=0;cl<4;cl++)
      bfr[cl] = *(const int4*)(wbase + (size_t)cl*16*FD + s*32);
#pragma unroll
    for (int gp=0;gp<4;gp++){
      short8 afrag = __builtin_bit_cast(short8,
          *(const int4*)(xbase + (size_t)gp*16*FD + s*32));
#pragma unroll
      for (int cl=0;cl<4;cl++)
        acc[gp][cl] = __builtin_amdgcn_mfma_f32_16x16x32_bf16(
            afrag, __builtin_bit_cast(short8, bfr[cl]), acc[gp][cl], 0, 0, 0);
    }
  }
#pragma unroll
  for (int gp=0;gp<4;gp++){
    const int rl  = nl + gp*16;               // local row base
    const int t   = rl >> 5;                  // m-tile of 32
    const int mj  = ((rl >> 4) & 1) * 16 + g*4;
    unsigned short* dst = hT + (size_t)b*BSLAB + (size_t)t*TILE_SH + mj;
#pragma unroll
    for (int cl=0;cl<4;cl++){
      const int o = w*64 + cl*16 + r16;
      uint2 u;
      u.x = (unsigned)f2bf(acc[gp][cl][0]) | ((unsigned)f2bf(acc[gp][cl][1])<<16);
      u.y = (unsigned)f2bf(acc[gp][cl][2]) | ((unsigned)f2bf(acc[gp][cl][3])<<16);
      *(uint2*)(dst + o*32) = u;
    }
  }
}

// ---------------------------------------------------------------------------
// K2: fused scores + exp + PV + normalize + ELU.
// Grid 256 = 8 XCD-affine batches x 32 n-tiles of 64 rows. 512 threads =
// 8 waves = 4 m-quarters (q) x 2 n-pairs (w); wave owns 2 n-tiles over its
// m-quarter (16 steps of 32). B-frag tiles staged via global_load_lds into
// 128 KB double-buffered LDS (each pair stages its own 16 KB tile, split by
// w), then read by ds_read_b128 -> zero VGPR pressure on B (R7-R9 were bound
// by compiler-serialized B loads in too few regs). Counted vmcnt(8) + raw
// s_barrier keeps adj/e prefetch in flight across barriers (never drain).
// ---------------------------------------------------------------------------
__global__ __launch_bounds__(512,2) void gat_fused(
    const int* __restrict__ adj,
    const float* __restrict__ e_src,
    const float* __restrict__ e_dst,
    const unsigned short* __restrict__ hT,
    float* __restrict__ out)
{
  __shared__ __align__(16) char smem[131072];     // 2 buf x 4 q-tiles x 16 KB
  __shared__ float rsum[4][4][16];                // [tile][q][16]

  const int tid = threadIdx.x;
  const int Wv  = tid >> 6;
  const int q   = Wv & 3;              // m-quarter
  const int w   = Wv >> 2;             // n-pair
  const int l   = tid & 63;
  const int r16 = l & 15, g = l >> 4;
  const int b   = blockIdx.x & 7;      // XCD-affine batch
  const int n0  = (blockIdx.x >> 3) << 6;        // 64 rows/block

  const int* adjR0 = adj + (size_t)(b*NN + n0 + w*32 + r16)*NN + q*512 + g*8;
  const int* adjR1 = adjR0 + (size_t)16*NN;
  const float* edB = e_dst + b*NN + q*512 + g*8;
  // gll source base (lane-resolved: +l*8 shorts = 16B/lane)
  const unsigned short* hTq = hT + (size_t)b*BSLAB + (size_t)q*16*TILE_SH
                                 + (size_t)w*4096 + l*8;
  char* ldsW       = smem + q*16384 + w*8192;    // stage dest (+buf*65536+i*1024)
  const char* ldsR = smem + q*16384;             // read base (+buf*65536)
  const float es0 = e_src[b*NN + n0 + w*32 + r16];
  const float es1 = e_src[b*NN + n0 + w*32 + 16 + r16];

  f32x4 acc0[16], acc1[16];
#pragma unroll
  for (int c=0;c<16;c++){ acc0[c] = (f32x4){0.f,0.f,0.f,0.f};
                          acc1[c] = (f32x4){0.f,0.f,0.f,0.f}; }
  float ps0 = 0.f, ps1 = 0.f;

  auto mkp = [&](i32x4 a0, i32x4 a1, float4 e0, float4 e1,
                 float es, float& ps)->short8{
    int   ai[8] = {a0[0],a0[1],a0[2],a0[3],a1[0],a1[1],a1[2],a1[3]};
    float ev[8] = {e0.x,e0.y,e0.z,e0.w,e1.x,e1.y,e1.z,e1.w};
    unsigned pt[8];
#pragma unroll
    for (int j=0;j<8;j++){
      float s = es + ev[j];
      s = fmaxf(s, ALPHA*s);                       // leaky relu
      float p = __expf(s);
      p = (ai[j] > 0) ? p : 0.f;
      unsigned ub = __builtin_bit_cast(unsigned, p) & 0xFFFF0000u;
      ps += __builtin_bit_cast(float, ub);         // rowsum of truncated P
      pt[j] = ub;
    }
    union { short8 v; unsigned u[4]; } A;
#pragma unroll
    for (int j=0;j<4;j++) A.u[j] = pt[2*j+1] | (pt[2*j] >> 16);
    return A.v;
  };

  // ---- prologue: adj(0), e(0), stage tile 0 -> buf0  (14 vm ops) ----
  i32x4 aj00,aj01, aj10,aj11;
  float4 eC0, eC1;
  {
    const i32x4* p0 = (const i32x4*)adjR0;
    aj00 = __builtin_nontemporal_load(p0);
    aj01 = __builtin_nontemporal_load(p0+1);
    const i32x4* p1 = (const i32x4*)adjR1;
    aj10 = __builtin_nontemporal_load(p1);
    aj11 = __builtin_nontemporal_load(p1+1);
    eC0 = *(const float4*)edB; eC1 = *(const float4*)(edB+4);
  }
#pragma unroll
  for (int i=0;i<8;i++) gll16(hTq + i*512, ldsW + i*1024);

  for (int t = 0; t < 16; ++t){
    const int cur = t & 1, nxt = cur ^ 1;
    const int ts  = (t < 15) ? t+1 : 15;           // stage target (tail dummy)
    // (1) stage tile ts into buf[nxt] : 8 gll16
    {
      const unsigned short* gsrc = hTq + (size_t)ts*TILE_SH;
      char* ld = ldsW + nxt*65536;
#pragma unroll
      for (int i=0;i<8;i++) gll16(gsrc + i*512, ld + i*1024);
    }
    // (2) wait: everything older than this step's 8 gll retired
    //     (= buf[cur] staged, adj/e for t landed). Never drains to 0.
    asm volatile("s_waitcnt vmcnt(8)" ::: "memory");
    __builtin_amdgcn_sched_barrier(0);
    __builtin_amdgcn_s_barrier();
    __builtin_amdgcn_sched_barrier(0);
    // (3) softmax fragments for step t (adj/e in regs)
    short8 pa0 = mkp(aj00,aj01, eC0,eC1, es0, ps0);
    short8 pa1 = mkp(aj10,aj11, eC0,eC1, es1, ps1);
    // (4) refill adj/e for t+1 (fly across the end barrier)
    const int tn = (t < 15) ? t+1 : 0;
    {
      const i32x4* p0 = (const i32x4*)(adjR0 + tn*32);
      aj00 = __builtin_nontemporal_load(p0);
      aj01 = __builtin_nontemporal_load(p0+1);
      const i32x4* p1 = (const i32x4*)(adjR1 + tn*32);
      aj10 = __builtin_nontemporal_load(p1);
      aj11 = __builtin_nontemporal_load(p1+1);
      const float* ep = edB + tn*32;
      eC0 = *(const float4*)ep; eC1 = *(const float4*)(ep+4);
    }
    // (5) ds_read + MFMA (compiler interleaves with fine lgkmcnt)
    {
      const char* rb = ldsR + cur*65536;
#pragma unroll
      for (int c=0;c<16;c++){
        int4 bv = *(const int4*)(rb + c*1024 + r16*64 + g*16);
        acc0[c] = __builtin_amdgcn_mfma_f32_16x16x32_bf16(
                    pa0, __builtin_bit_cast(short8, bv), acc0[c], 0, 0, 0);
        acc1[c] = __builtin_amdgcn_mfma_f32_16x16x32_bf16(
                    pa1, __builtin_bit_cast(short8, bv), acc1[c], 0, 0, 0);
      }
    }
    // (6) end barrier: protects buf[cur] from next step's staging (WAR)
    __builtin_amdgcn_sched_barrier(0);
    __builtin_amdgcn_s_barrier();
    __builtin_amdgcn_sched_barrier(0);
  }
  // keep tail dummy prefetches alive (uniform vm counts)
  asm volatile("" :: "v"(aj00[0]),"v"(aj10[0]),"v"(eC0.x),"v"(eC1.x));

  // ---- partial rowsums ----
  float rs0 = ps0, rs1 = ps1;
  rs0 += __shfl_xor(rs0, 16); rs0 += __shfl_xor(rs0, 32);
  rs1 += __shfl_xor(rs1, 16); rs1 += __shfl_xor(rs1, 32);
  if (l < 16){ rsum[w*2][q][l] = rs0; rsum[w*2+1][q][l] = rs1; }
  __syncthreads();

  float t0 = rsum[w*2  ][0][r16] + rsum[w*2  ][1][r16]
           + rsum[w*2  ][2][r16] + rsum[w*2  ][3][r16];
  float t1 = rsum[w*2+1][0][r16] + rsum[w*2+1][1][r16]
           + rsum[w*2+1][2][r16] + rsum[w*2+1][3][r16];
  float inv0[4], inv1[4];
#pragma unroll
  for (int r=0;r<4;r++){ inv0[r] = 1.0f / __shfl(t0, g*4 + r);
                         inv1[r] = 1.0f / __shfl(t1, g*4 + r); }

  // ---- 4 combine rounds, red[] aliased onto the staging LDS (64 KB) ----
  f32x4* red = (f32x4*)smem;                       // [w][c][q][l]
#define RED(W_,C_,Q_,L_) red[(((W_)*8 + (C_))*4 + (Q_))*64 + (L_)]
#pragma unroll
  for (int rd = 0; rd < 4; ++rd){
    const int s = rd >> 1, h = rd & 1;
    f32x4* accp = s ? acc1 : acc0;
#pragma unroll
    for (int c=0;c<8;c++) RED(w,c,q,l) = accp[h*8+c];
    __syncthreads();
    const float* inv_ = s ? inv1 : inv0;
    float* outB = out + (size_t)(b*NN + n0 + w*32 + s*16)*FD;
#pragma unroll
    for (int i=0;i<2;i++){
      const int c = q*2 + i;
      f32x4 v = RED(w,c,0,l) + RED(w,c,1,l) + RED(w,c,2,l) + RED(w,c,3,l);
#pragma unroll
      for (int r=0;r<4;r++){
        float o = v[r] * inv_[r];
        o = o > 0.f ? o : (__expf(o) - 1.f);       // ELU
        __builtin_nontemporal_store(o,
            &outB[(size_t)(g*4 + r)*FD + (h*8 + c)*16 + r16]);
      }
    }
    __syncthreads();
  }
#undef RED
}

// ---------------------------------------------------------------------------
extern "C" void kernel_launch(void* const* d_in, const int* in_sizes, int n_in,
                              void* d_out, int out_size, void* d_ws, size_t ws_size,
                              hipStream_t stream)
{
  const float* x   = (const float*)d_in[0];
  const int*   adj = (const int*)  d_in[1];
  const float* W   = (const float*)d_in[2];
  const float* a   = (const float*)d_in[3];
  float* out = (float*)d_out;

  char* ws = (char*)d_ws;
  size_t off = 0;
  auto alloc = [&](size_t bytes)->char*{
    char* p = ws + off; off += (bytes + 255) & ~(size_t)255; return p;
  };
  unsigned short* WT    = (unsigned short*)alloc((size_t)FD*FD*2);
  float*          w_src = (float*)alloc(FD*4);
  float*          w_dst = (float*)alloc(FD*4);
  float*          e_src = (float*)alloc((size_t)BATCH*NN*4);
  float*          e_dst = (float*)alloc((size_t)BATCH*NN*4);
  unsigned short* xb    = (unsigned short*)alloc((size_t)BATCH*NN*FD*2);
  unsigned short* hT    = (unsigned short*)alloc((size_t)BATCH*NN*FD*2);

  prep_w   <<<FD,              64,  0, stream>>>(W, a, w_src, w_dst, WT);
  prep_x   <<<(BATCH*NN)/4,    256, 0, stream>>>(x, w_src, w_dst, xb, e_src, e_dst);
  gemm_h   <<<(BATCH*NN)/64,   256, 0, stream>>>(xb, WT, hT);
  gat_fused<<<(BATCH*NN)/64,   512, 0, stream>>>(adj, e_src, e_dst, hT, out);
}

// Round 11
// 69.440 us; speedup vs baseline: 2.8677x; 1.1706x over previous
//
#include <hip/hip_runtime.h>

#define ALPHA 0.2f
#define BATCH 8
#define NN    2048
#define FD    256
// hT layout: [b][t=m/32][o=0..255][mj=0..31], short. 8192 shorts (16KB) per tile.
#define TILE_SH 8192
#define BSLAB   (FD*NN)          // shorts per batch slab (1 MB)

typedef __attribute__((ext_vector_type(8))) short short8;
typedef __attribute__((ext_vector_type(4))) float f32x4;
typedef __attribute__((ext_vector_type(4))) int   i32x4;

__device__ __forceinline__ unsigned short f2bf(float f){
  unsigned u = __builtin_bit_cast(unsigned, f);
  return (unsigned short)((u + 0x7FFFu + ((u>>16)&1u)) >> 16);   // RTN-even
}
__device__ __forceinline__ float dot4(float4 a, float4 b){
  return a.x*b.x + a.y*b.y + a.z*b.z + a.w*b.w;
}
// async global->LDS, 16B/lane: dest = uniform base + lane*16; src is per-lane.
__device__ __forceinline__ void gll16(const void* g, void* l){
  __builtin_amdgcn_global_load_lds(
      (const __attribute__((address_space(1))) unsigned int*)g,
      (__attribute__((address_space(3))) unsigned int*)l, 16, 0, 0);
}

// ---------------------------------------------------------------------------
// K0: w_src = W @ a_src, w_dst = W @ a_dst (exact fp32), WT[o][k] = bf16(W[k][o])
// ---------------------------------------------------------------------------
__global__ __launch_bounds__(64) void prep_w(
    const float* __restrict__ W, const float* __restrict__ a,
    float* __restrict__ w_src, float* __restrict__ w_dst,
    unsigned short* __restrict__ WT)
{
  const int k = blockIdx.x;
  const int l = threadIdx.x;
  float4 wv = *(const float4*)(W + k*FD + l*4);
  float4 as = *(const float4*)(a + l*4);
  float4 ad = *(const float4*)(a + FD + l*4);
  float s = dot4(wv, as);
  float d = dot4(wv, ad);
#pragma unroll
  for (int m=1;m<64;m<<=1){ s += __shfl_xor(s, m); d += __shfl_xor(d, m); }
  if (l == 0){ w_src[k] = s; w_dst[k] = d; }
  WT[(l*4+0)*FD + k] = f2bf(wv.x);
  WT[(l*4+1)*FD + k] = f2bf(wv.y);
  WT[(l*4+2)*FD + k] = f2bf(wv.z);
  WT[(l*4+3)*FD + k] = f2bf(wv.w);
}

// ---------------------------------------------------------------------------
// K1 (fused prep_x + gemm_h): reads x fp32 ONCE; produces
//   hT (bf16, fragment-linear tiled) + e_src/e_dst (exact fp32 dots).
// 64-row XCD-affine blocks (grid 256). A-frags converted fp32->bf16 in-reg
// (same RTN as before -> bit-identical hT). e dots ride the same x loads;
// w_src/w_dst are 1KB L1-hot.
// ---------------------------------------------------------------------------
__global__ __launch_bounds__(256) void gemm_he(
    const float* __restrict__ x,
    const float* __restrict__ w_src, const float* __restrict__ w_dst,
    const unsigned short* __restrict__ WT,
    unsigned short* __restrict__ hT,
    float* __restrict__ e_src, float* __restrict__ e_dst)
{
  const int tid = threadIdx.x;
  const int w = tid >> 6, l = tid & 63;
  const int r16 = l & 15, g = l >> 4;
  const int b  = blockIdx.x & 7;
  const int nl = (blockIdx.x >> 3) << 6;      // 64 local rows
  const int row0 = b*NN + nl;

  f32x4 acc[4][4];                            // [row-group][cl]
#pragma unroll
  for (int gp=0;gp<4;gp++)
#pragma unroll
    for (int c=0;c<4;c++) acc[gp][c] = (f32x4){0.f,0.f,0.f,0.f};
  float esp[4] = {0.f,0.f,0.f,0.f};
  float edp[4] = {0.f,0.f,0.f,0.f};

  const float* xbase = x + (size_t)(row0 + r16)*FD + g*8;
  const unsigned short* wbase = WT + (size_t)(w*64 + r16)*FD + g*8;
#pragma unroll
  for (int s=0;s<8;s++){
    int4 bfr[4];
#pragma unroll
    for (int cl=0;cl<4;cl++)
      bfr[cl] = *(const int4*)(wbase + (size_t)cl*16*FD + s*32);
    float4 ws0 = *(const float4*)(w_src + s*32 + g*8);
    float4 ws1 = *(const float4*)(w_src + s*32 + g*8 + 4);
    float4 wd0 = *(const float4*)(w_dst + s*32 + g*8);
    float4 wd1 = *(const float4*)(w_dst + s*32 + g*8 + 4);
#pragma unroll
    for (int gp=0;gp<4;gp++){
      float4 x0 = *(const float4*)(xbase + (size_t)gp*16*FD + s*32);
      float4 x1 = *(const float4*)(xbase + (size_t)gp*16*FD + s*32 + 4);
      esp[gp] += dot4(x0,ws0) + dot4(x1,ws1);
      edp[gp] += dot4(x0,wd0) + dot4(x1,wd1);
      union { short8 v; unsigned short u[8]; } A;
      A.u[0]=f2bf(x0.x); A.u[1]=f2bf(x0.y); A.u[2]=f2bf(x0.z); A.u[3]=f2bf(x0.w);
      A.u[4]=f2bf(x1.x); A.u[5]=f2bf(x1.y); A.u[6]=f2bf(x1.z); A.u[7]=f2bf(x1.w);
#pragma unroll
      for (int cl=0;cl<4;cl++)
        acc[gp][cl] = __builtin_amdgcn_mfma_f32_16x16x32_bf16(
            A.v, __builtin_bit_cast(short8, bfr[cl]), acc[gp][cl], 0, 0, 0);
    }
  }
  // ---- e reduce (sum over g groups) + write by wave 0 ----
#pragma unroll
  for (int gp=0;gp<4;gp++){
    float es_ = esp[gp], ed_ = edp[gp];
    es_ += __shfl_xor(es_, 16); es_ += __shfl_xor(es_, 32);
    ed_ += __shfl_xor(ed_, 16); ed_ += __shfl_xor(ed_, 32);
    if (w == 0 && l < 16){
      e_src[row0 + gp*16 + l] = es_;
      e_dst[row0 + gp*16 + l] = ed_;
    }
  }
  // ---- hT write (fragment-linear tiled) ----
#pragma unroll
  for (int gp=0;gp<4;gp++){
    const int rl  = nl + gp*16;               // local row base
    const int t   = rl >> 5;                  // m-tile of 32
    const int mj  = ((rl >> 4) & 1) * 16 + g*4;
    unsigned short* dst = hT + (size_t)b*BSLAB + (size_t)t*TILE_SH + mj;
#pragma unroll
    for (int cl=0;cl<4;cl++){
      const int o = w*64 + cl*16 + r16;
      uint2 u;
      u.x = (unsigned)f2bf(acc[gp][cl][0]) | ((unsigned)f2bf(acc[gp][cl][1])<<16);
      u.y = (unsigned)f2bf(acc[gp][cl][2]) | ((unsigned)f2bf(acc[gp][cl][3])<<16);
      *(uint2*)(dst + o*32) = u;
    }
  }
}

// ---------------------------------------------------------------------------
// K2: fused scores + exp + PV + normalize + ELU.  (R10 structure, +setprio)
// Grid 256 = 8 XCD-affine batches x 32 n-tiles of 64 rows. 512 threads =
// 8 waves = 4 m-quarters (q) x 2 n-pairs (w); wave owns 2 n-tiles over its
// m-quarter (16 steps of 32). B-frag tiles staged via global_load_lds into
// 128 KB double-buffered LDS, read by ds_read_b128. Counted vmcnt(8) + raw
// s_barrier; adj/e prefetch flies across barriers (never drained early).
// ---------------------------------------------------------------------------
__global__ __launch_bounds__(512,2) void gat_fused(
    const int* __restrict__ adj,
    const float* __restrict__ e_src,
    const float* __restrict__ e_dst,
    const unsigned short* __restrict__ hT,
    float* __restrict__ out)
{
  __shared__ __align__(16) char smem[131072];     // 2 buf x 4 q-tiles x 16 KB
  __shared__ float rsum[4][4][16];                // [tile][q][16]

  const int tid = threadIdx.x;
  const int Wv  = tid >> 6;
  const int q   = Wv & 3;              // m-quarter
  const int w   = Wv >> 2;             // n-pair
  const int l   = tid & 63;
  const int r16 = l & 15, g = l >> 4;
  const int b   = blockIdx.x & 7;      // XCD-affine batch
  const int n0  = (blockIdx.x >> 3) << 6;        // 64 rows/block

  const int* adjR0 = adj + (size_t)(b*NN + n0 + w*32 + r16)*NN + q*512 + g*8;
  const int* adjR1 = adjR0 + (size_t)16*NN;
  const float* edB = e_dst + b*NN + q*512 + g*8;
  const unsigned short* hTq = hT + (size_t)b*BSLAB + (size_t)q*16*TILE_SH
                                 + (size_t)w*4096 + l*8;
  char* ldsW       = smem + q*16384 + w*8192;    // stage dest (+buf*65536+i*1024)
  const char* ldsR = smem + q*16384;             // read base (+buf*65536)
  const float es0 = e_src[b*NN + n0 + w*32 + r16];
  const float es1 = e_src[b*NN + n0 + w*32 + 16 + r16];

  f32x4 acc0[16], acc1[16];
#pragma unroll
  for (int c=0;c<16;c++){ acc0[c] = (f32x4){0.f,0.f,0.f,0.f};
                          acc1[c] = (f32x4){0.f,0.f,0.f,0.f}; }
  float ps0 = 0.f, ps1 = 0.f;

  auto mkp = [&](i32x4 a0, i32x4 a1, float4 e0, float4 e1,
                 float es, float& ps)->short8{
    int   ai[8] = {a0[0],a0[1],a0[2],a0[3],a1[0],a1[1],a1[2],a1[3]};
    float ev[8] = {e0.x,e0.y,e0.z,e0.w,e1.x,e1.y,e1.z,e1.w};
    unsigned pt[8];
#pragma unroll
    for (int j=0;j<8;j++){
      float s = es + ev[j];
      s = fmaxf(s, ALPHA*s);                       // leaky relu
      float p = __expf(s);
      p = (ai[j] > 0) ? p : 0.f;
      unsigned ub = __builtin_bit_cast(unsigned, p) & 0xFFFF0000u;
      ps += __builtin_bit_cast(float, ub);         // rowsum of truncated P
      pt[j] = ub;
    }
    union { short8 v; unsigned u[4]; } A;
#pragma unroll
    for (int j=0;j<4;j++) A.u[j] = pt[2*j+1] | (pt[2*j] >> 16);
    return A.v;
  };

  // ---- prologue: adj(0), e(0), stage tile 0 -> buf0 ----
  i32x4 aj00,aj01, aj10,aj11;
  float4 eC0, eC1;
  {
    const i32x4* p0 = (const i32x4*)adjR0;
    aj00 = __builtin_nontemporal_load(p0);
    aj01 = __builtin_nontemporal_load(p0+1);
    const i32x4* p1 = (const i32x4*)adjR1;
    aj10 = __builtin_nontemporal_load(p1);
    aj11 = __builtin_nontemporal_load(p1+1);
    eC0 = *(const float4*)edB; eC1 = *(const float4*)(edB+4);
  }
#pragma unroll
  for (int i=0;i<8;i++) gll16(hTq + i*512, ldsW + i*1024);

  for (int t = 0; t < 16; ++t){
    const int cur = t & 1, nxt = cur ^ 1;
    const int ts  = (t < 15) ? t+1 : 15;           // stage target (tail dummy)
    // (1) stage tile ts into buf[nxt] : 8 gll16
    {
      const unsigned short* gsrc = hTq + (size_t)ts*TILE_SH;
      char* ld = ldsW + nxt*65536;
#pragma unroll
      for (int i=0;i<8;i++) gll16(gsrc + i*512, ld + i*1024);
    }
    // (2) wait: everything older than this step's 8 gll retired.
    asm volatile("s_waitcnt vmcnt(8)" ::: "memory");
    __builtin_amdgcn_sched_barrier(0);
    __builtin_amdgcn_s_barrier();
    __builtin_amdgcn_sched_barrier(0);
    // (3) softmax fragments for step t (adj/e in regs)
    short8 pa0 = mkp(aj00,aj01, eC0,eC1, es0, ps0);
    short8 pa1 = mkp(aj10,aj11, eC0,eC1, es1, ps1);
    // (4) refill adj/e for t+1 (fly across the end barrier)
    const int tn = (t < 15) ? t+1 : 0;
    {
      const i32x4* p0 = (const i32x4*)(adjR0 + tn*32);
      aj00 = __builtin_nontemporal_load(p0);
      aj01 = __builtin_nontemporal_load(p0+1);
      const i32x4* p1 = (const i32x4*)(adjR1 + tn*32);
      aj10 = __builtin_nontemporal_load(p1);
      aj11 = __builtin_nontemporal_load(p1+1);
      const float* ep = edB + tn*32;
      eC0 = *(const float4*)ep; eC1 = *(const float4*)(ep+4);
    }
    // (5) ds_read + MFMA (setprio: favor MFMA-phase wave on the SIMD)
    {
      const char* rb = ldsR + cur*65536;
      __builtin_amdgcn_s_setprio(1);
#pragma unroll
      for (int c=0;c<16;c++){
        int4 bv = *(const int4*)(rb + c*1024 + r16*64 + g*16);
        acc0[c] = __builtin_amdgcn_mfma_f32_16x16x32_bf16(
                    pa0, __builtin_bit_cast(short8, bv), acc0[c], 0, 0, 0);
        acc1[c] = __builtin_amdgcn_mfma_f32_16x16x32_bf16(
                    pa1, __builtin_bit_cast(short8, bv), acc1[c], 0, 0, 0);
      }
      __builtin_amdgcn_s_setprio(0);
    }
    // (6) end barrier: protects buf[cur] from next step's staging (WAR)
    __builtin_amdgcn_sched_barrier(0);
    __builtin_amdgcn_s_barrier();
    __builtin_amdgcn_sched_barrier(0);
  }
  asm volatile("" :: "v"(aj00[0]),"v"(aj10[0]),"v"(eC0.x),"v"(eC1.x));

  // ---- partial rowsums ----
  float rs0 = ps0, rs1 = ps1;
  rs0 += __shfl_xor(rs0, 16); rs0 += __shfl_xor(rs0, 32);
  rs1 += __shfl_xor(rs1, 16); rs1 += __shfl_xor(rs1, 32);
  if (l < 16){ rsum[w*2][q][l] = rs0; rsum[w*2+1][q][l] = rs1; }
  __syncthreads();

  float t0 = rsum[w*2  ][0][r16] + rsum[w*2  ][1][r16]
           + rsum[w*2  ][2][r16] + rsum[w*2  ][3][r16];
  float t1 = rsum[w*2+1][0][r16] + rsum[w*2+1][1][r16]
           + rsum[w*2+1][2][r16] + rsum[w*2+1][3][r16];
  float inv0[4], inv1[4];
#pragma unroll
  for (int r=0;r<4;r++){ inv0[r] = 1.0f / __shfl(t0, g*4 + r);
                         inv1[r] = 1.0f / __shfl(t1, g*4 + r); }

  // ---- 4 combine rounds, red[] aliased onto the staging LDS (64 KB) ----
  f32x4* red = (f32x4*)smem;                       // [w][c][q][l]
#define RED(W_,C_,Q_,L_) red[(((W_)*8 + (C_))*4 + (Q_))*64 + (L_)]
#pragma unroll
  for (int rd = 0; rd < 4; ++rd){
    const int s = rd >> 1, h = rd & 1;
    f32x4* accp = s ? acc1 : acc0;
#pragma unroll
    for (int c=0;c<8;c++) RED(w,c,q,l) = accp[h*8+c];
    __syncthreads();
    const float* inv_ = s ? inv1 : inv0;
    float* outB = out + (size_t)(b*NN + n0 + w*32 + s*16)*FD;
#pragma unroll
    for (int i=0;i<2;i++){
      const int c = q*2 + i;
      f32x4 v = RED(w,c,0,l) + RED(w,c,1,l) + RED(w,c,2,l) + RED(w,c,3,l);
#pragma unroll
      for (int r=0;r<4;r++){
        float o = v[r] * inv_[r];
        o = o > 0.f ? o : (__expf(o) - 1.f);       // ELU
        __builtin_nontemporal_store(o,
            &outB[(size_t)(g*4 + r)*FD + (h*8 + c)*16 + r16]);
      }
    }
    __syncthreads();
  }
#undef RED
}

// ---------------------------------------------------------------------------
extern "C" void kernel_launch(void* const* d_in, const int* in_sizes, int n_in,
                              void* d_out, int out_size, void* d_ws, size_t ws_size,
                              hipStream_t stream)
{
  const float* x   = (const float*)d_in[0];
  const int*   adj = (const int*)  d_in[1];
  const float* W   = (const float*)d_in[2];
  const float* a   = (const float*)d_in[3];
  float* out = (float*)d_out;

  char* ws = (char*)d_ws;
  size_t off = 0;
  auto alloc = [&](size_t bytes)->char*{
    char* p = ws + off; off += (bytes + 255) & ~(size_t)255; return p;
  };
  unsigned short* WT    = (unsigned short*)alloc((size_t)FD*FD*2);
  float*          w_src = (float*)alloc(FD*4);
  float*          w_dst = (float*)alloc(FD*4);
  float*          e_src = (float*)alloc((size_t)BATCH*NN*4);
  float*          e_dst = (float*)alloc((size_t)BATCH*NN*4);
  unsigned short* hT    = (unsigned short*)alloc((size_t)BATCH*NN*FD*2);

  prep_w   <<<FD,              64,  0, stream>>>(W, a, w_src, w_dst, WT);
  gemm_he  <<<(BATCH*NN)/64,   256, 0, stream>>>(x, w_src, w_dst, WT, hT, e_src, e_dst);
  gat_fused<<<(BATCH*NN)/64,   512, 0, stream>>>(adj, e_src, e_dst, hT, out);
}

// Round 12
// 68.199 us; speedup vs baseline: 2.9199x; 1.0182x over previous
//
#include <hip/hip_runtime.h>

#define ALPHA 0.2f
#define BATCH 8
#define NN    2048
#define FD    256
// hT layout: [b][t=m/32][o=0..255][mj=0..31], short. 8192 shorts (16KB) per tile.
#define TILE_SH 8192
#define BSLAB   (FD*NN)          // shorts per batch slab (1 MB)

typedef __attribute__((ext_vector_type(8))) short short8;
typedef __attribute__((ext_vector_type(4))) float f32x4;
typedef __attribute__((ext_vector_type(4))) int   i32x4;

__device__ __forceinline__ unsigned short f2bf(float f){
  unsigned u = __builtin_bit_cast(unsigned, f);
  return (unsigned short)((u + 0x7FFFu + ((u>>16)&1u)) >> 16);   // RTN-even
}
__device__ __forceinline__ float dot4(float4 a, float4 b){
  return a.x*b.x + a.y*b.y + a.z*b.z + a.w*b.w;
}
// async global->LDS, 16B/lane: dest = uniform base + lane*16; src is per-lane.
__device__ __forceinline__ void gll16(const void* g, void* l){
  __builtin_amdgcn_global_load_lds(
      (const __attribute__((address_space(1))) unsigned int*)g,
      (__attribute__((address_space(3))) unsigned int*)l, 16, 0, 0);
}

// ---------------------------------------------------------------------------
// K0: w_src = W @ a_src, w_dst = W @ a_dst (exact fp32), WT[o][k] = bf16(W[k][o])
// ---------------------------------------------------------------------------
__global__ __launch_bounds__(64) void prep_w(
    const float* __restrict__ W, const float* __restrict__ a,
    float* __restrict__ w_src, float* __restrict__ w_dst,
    unsigned short* __restrict__ WT)
{
  const int k = blockIdx.x;
  const int l = threadIdx.x;
  float4 wv = *(const float4*)(W + k*FD + l*4);
  float4 as = *(const float4*)(a + l*4);
  float4 ad = *(const float4*)(a + FD + l*4);
  float s = dot4(wv, as);
  float d = dot4(wv, ad);
#pragma unroll
  for (int m=1;m<64;m<<=1){ s += __shfl_xor(s, m); d += __shfl_xor(d, m); }
  if (l == 0){ w_src[k] = s; w_dst[k] = d; }
  WT[(l*4+0)*FD + k] = f2bf(wv.x);
  WT[(l*4+1)*FD + k] = f2bf(wv.y);
  WT[(l*4+2)*FD + k] = f2bf(wv.z);
  WT[(l*4+3)*FD + k] = f2bf(wv.w);
}

// ---------------------------------------------------------------------------
// K1 (fused prep_x + gemm_h): reads x fp32 ONCE; produces
//   hT (bf16, fragment-linear tiled) + e_src/e_dst (exact fp32 dots).
// 64-row XCD-affine blocks (grid 256).
// ---------------------------------------------------------------------------
__global__ __launch_bounds__(256) void gemm_he(
    const float* __restrict__ x,
    const float* __restrict__ w_src, const float* __restrict__ w_dst,
    const unsigned short* __restrict__ WT,
    unsigned short* __restrict__ hT,
    float* __restrict__ e_src, float* __restrict__ e_dst)
{
  const int tid = threadIdx.x;
  const int w = tid >> 6, l = tid & 63;
  const int r16 = l & 15, g = l >> 4;
  const int b  = blockIdx.x & 7;
  const int nl = (blockIdx.x >> 3) << 6;      // 64 local rows
  const int row0 = b*NN + nl;

  f32x4 acc[4][4];                            // [row-group][cl]
#pragma unroll
  for (int gp=0;gp<4;gp++)
#pragma unroll
    for (int c=0;c<4;c++) acc[gp][c] = (f32x4){0.f,0.f,0.f,0.f};
  float esp[4] = {0.f,0.f,0.f,0.f};
  float edp[4] = {0.f,0.f,0.f,0.f};

  const float* xbase = x + (size_t)(row0 + r16)*FD + g*8;
  const unsigned short* wbase = WT + (size_t)(w*64 + r16)*FD + g*8;
#pragma unroll
  for (int s=0;s<8;s++){
    int4 bfr[4];
#pragma unroll
    for (int cl=0;cl<4;cl++)
      bfr[cl] = *(const int4*)(wbase + (size_t)cl*16*FD + s*32);
    float4 ws0 = *(const float4*)(w_src + s*32 + g*8);
    float4 ws1 = *(const float4*)(w_src + s*32 + g*8 + 4);
    float4 wd0 = *(const float4*)(w_dst + s*32 + g*8);
    float4 wd1 = *(const float4*)(w_dst + s*32 + g*8 + 4);
#pragma unroll
    for (int gp=0;gp<4;gp++){
      float4 x0 = *(const float4*)(xbase + (size_t)gp*16*FD + s*32);
      float4 x1 = *(const float4*)(xbase + (size_t)gp*16*FD + s*32 + 4);
      esp[gp] += dot4(x0,ws0) + dot4(x1,ws1);
      edp[gp] += dot4(x0,wd0) + dot4(x1,wd1);
      union { short8 v; unsigned short u[8]; } A;
      A.u[0]=f2bf(x0.x); A.u[1]=f2bf(x0.y); A.u[2]=f2bf(x0.z); A.u[3]=f2bf(x0.w);
      A.u[4]=f2bf(x1.x); A.u[5]=f2bf(x1.y); A.u[6]=f2bf(x1.z); A.u[7]=f2bf(x1.w);
#pragma unroll
      for (int cl=0;cl<4;cl++)
        acc[gp][cl] = __builtin_amdgcn_mfma_f32_16x16x32_bf16(
            A.v, __builtin_bit_cast(short8, bfr[cl]), acc[gp][cl], 0, 0, 0);
    }
  }
  // ---- e reduce (sum over g groups) + write by wave 0 ----
#pragma unroll
  for (int gp=0;gp<4;gp++){
    float es_ = esp[gp], ed_ = edp[gp];
    es_ += __shfl_xor(es_, 16); es_ += __shfl_xor(es_, 32);
    ed_ += __shfl_xor(ed_, 16); ed_ += __shfl_xor(ed_, 32);
    if (w == 0 && l < 16){
      e_src[row0 + gp*16 + l] = es_;
      e_dst[row0 + gp*16 + l] = ed_;
    }
  }
  // ---- hT write (fragment-linear tiled) ----
#pragma unroll
  for (int gp=0;gp<4;gp++){
    const int rl  = nl + gp*16;               // local row base
    const int t   = rl >> 5;                  // m-tile of 32
    const int mj  = ((rl >> 4) & 1) * 16 + g*4;
    unsigned short* dst = hT + (size_t)b*BSLAB + (size_t)t*TILE_SH + mj;
#pragma unroll
    for (int cl=0;cl<4;cl++){
      const int o = w*64 + cl*16 + r16;
      uint2 u;
      u.x = (unsigned)f2bf(acc[gp][cl][0]) | ((unsigned)f2bf(acc[gp][cl][1])<<16);
      u.y = (unsigned)f2bf(acc[gp][cl][2]) | ((unsigned)f2bf(acc[gp][cl][3])<<16);
      *(uint2*)(dst + o*32) = u;
    }
  }
}

// ---------------------------------------------------------------------------
// K2: fused scores + exp + PV + normalize + ELU.  (R11 structure + LDS XOR
// swizzle on the staged B-frag tiles: read offset (r16*64+g*16) XOR'd on
// bits 4-5 with (r16>>1)&3 -> each 16-lane group spreads 2 dwords/bank
// instead of 4-way conflicts. gll dest stays LINEAR; the global SOURCE is
// pre-swizzled per lane (XOR field depends only on lane id) -> both-sides
// involution, data bit-identical.)
// ---------------------------------------------------------------------------
__global__ __launch_bounds__(512,2) void gat_fused(
    const int* __restrict__ adj,
    const float* __restrict__ e_src,
    const float* __restrict__ e_dst,
    const unsigned short* __restrict__ hT,
    float* __restrict__ out)
{
  __shared__ __align__(16) char smem[131072];     // 2 buf x 4 q-tiles x 16 KB
  __shared__ float rsum[4][4][16];                // [tile][q][16]

  const int tid = threadIdx.x;
  const int Wv  = tid >> 6;
  const int q   = Wv & 3;              // m-quarter
  const int w   = Wv >> 2;             // n-pair
  const int l   = tid & 63;
  const int r16 = l & 15, g = l >> 4;
  const int b   = blockIdx.x & 7;      // XCD-affine batch
  const int n0  = (blockIdx.x >> 3) << 6;        // 64 rows/block

  const int* adjR0 = adj + (size_t)(b*NN + n0 + w*32 + r16)*NN + q*512 + g*8;
  const int* adjR1 = adjR0 + (size_t)16*NN;
  const float* edB = e_dst + b*NN + q*512 + g*8;
  // gll source: lane byte-offset pre-swizzled (involution on bits 4-5)
  const int lsw = ((l*16) ^ (((l>>3)&3)<<4)) >> 1;   // in shorts
  const unsigned short* hTq = hT + (size_t)b*BSLAB + (size_t)q*16*TILE_SH
                                 + (size_t)w*4096 + lsw;
  char* ldsW       = smem + q*16384 + w*8192;    // stage dest (+buf*65536+i*1024)
  const char* ldsR = smem + q*16384;             // read base (+buf*65536)
  // swizzled B-frag read offset within a 1KB o-subtile
  const int hoff = (r16*64 + g*16) ^ (((r16>>1)&3)<<4);
  const float es0 = e_src[b*NN + n0 + w*32 + r16];
  const float es1 = e_src[b*NN + n0 + w*32 + 16 + r16];

  f32x4 acc0[16], acc1[16];
#pragma unroll
  for (int c=0;c<16;c++){ acc0[c] = (f32x4){0.f,0.f,0.f,0.f};
                          acc1[c] = (f32x4){0.f,0.f,0.f,0.f}; }
  float ps0 = 0.f, ps1 = 0.f;

  auto mkp = [&](i32x4 a0, i32x4 a1, float4 e0, float4 e1,
                 float es, float& ps)->short8{
    int   ai[8] = {a0[0],a0[1],a0[2],a0[3],a1[0],a1[1],a1[2],a1[3]};
    float ev[8] = {e0.x,e0.y,e0.z,e0.w,e1.x,e1.y,e1.z,e1.w};
    unsigned pt[8];
#pragma unroll
    for (int j=0;j<8;j++){
      float s = es + ev[j];
      s = fmaxf(s, ALPHA*s);                       // leaky relu
      float p = __expf(s);
      p = (ai[j] > 0) ? p : 0.f;
      unsigned ub = __builtin_bit_cast(unsigned, p) & 0xFFFF0000u;
      ps += __builtin_bit_cast(float, ub);         // rowsum of truncated P
      pt[j] = ub;
    }
    union { short8 v; unsigned u[4]; } A;
#pragma unroll
    for (int j=0;j<4;j++) A.u[j] = pt[2*j+1] | (pt[2*j] >> 16);
    return A.v;
  };

  // ---- prologue: adj(0), e(0), stage tile 0 -> buf0 ----
  i32x4 aj00,aj01, aj10,aj11;
  float4 eC0, eC1;
  {
    const i32x4* p0 = (const i32x4*)adjR0;
    aj00 = __builtin_nontemporal_load(p0);
    aj01 = __builtin_nontemporal_load(p0+1);
    const i32x4* p1 = (const i32x4*)adjR1;
    aj10 = __builtin_nontemporal_load(p1);
    aj11 = __builtin_nontemporal_load(p1+1);
    eC0 = *(const float4*)edB; eC1 = *(const float4*)(edB+4);
  }
#pragma unroll
  for (int i=0;i<8;i++) gll16(hTq + i*512, ldsW + i*1024);

  for (int t = 0; t < 16; ++t){
    const int cur = t & 1, nxt = cur ^ 1;
    const int ts  = (t < 15) ? t+1 : 15;           // stage target (tail dummy)
    // (1) stage tile ts into buf[nxt] : 8 gll16
    {
      const unsigned short* gsrc = hTq + (size_t)ts*TILE_SH;
      char* ld = ldsW + nxt*65536;
#pragma unroll
      for (int i=0;i<8;i++) gll16(gsrc + i*512, ld + i*1024);
    }
    // (2) wait: everything older than this step's 8 gll retired.
    asm volatile("s_waitcnt vmcnt(8)" ::: "memory");
    __builtin_amdgcn_sched_barrier(0);
    __builtin_amdgcn_s_barrier();
    __builtin_amdgcn_sched_barrier(0);
    // (3) softmax fragments for step t (adj/e in regs)
    short8 pa0 = mkp(aj00,aj01, eC0,eC1, es0, ps0);
    short8 pa1 = mkp(aj10,aj11, eC0,eC1, es1, ps1);
    // (4) refill adj/e for t+1 (fly across the end barrier)
    const int tn = (t < 15) ? t+1 : 0;
    {
      const i32x4* p0 = (const i32x4*)(adjR0 + tn*32);
      aj00 = __builtin_nontemporal_load(p0);
      aj01 = __builtin_nontemporal_load(p0+1);
      const i32x4* p1 = (const i32x4*)(adjR1 + tn*32);
      aj10 = __builtin_nontemporal_load(p1);
      aj11 = __builtin_nontemporal_load(p1+1);
      const float* ep = edB + tn*32;
      eC0 = *(const float4*)ep; eC1 = *(const float4*)(ep+4);
    }
    // (5) ds_read (swizzled, conflict-free) + MFMA
    {
      const char* rb = ldsR + cur*65536;
      __builtin_amdgcn_s_setprio(1);
#pragma unroll
      for (int c=0;c<16;c++){
        int4 bv = *(const int4*)(rb + c*1024 + hoff);
        acc0[c] = __builtin_amdgcn_mfma_f32_16x16x32_bf16(
                    pa0, __builtin_bit_cast(short8, bv), acc0[c], 0, 0, 0);
        acc1[c] = __builtin_amdgcn_mfma_f32_16x16x32_bf16(
                    pa1, __builtin_bit_cast(short8, bv), acc1[c], 0, 0, 0);
      }
      __builtin_amdgcn_s_setprio(0);
    }
    // (6) end barrier: protects buf[cur] from next step's staging (WAR)
    __builtin_amdgcn_sched_barrier(0);
    __builtin_amdgcn_s_barrier();
    __builtin_amdgcn_sched_barrier(0);
  }
  asm volatile("" :: "v"(aj00[0]),"v"(aj10[0]),"v"(eC0.x),"v"(eC1.x));

  // ---- partial rowsums ----
  float rs0 = ps0, rs1 = ps1;
  rs0 += __shfl_xor(rs0, 16); rs0 += __shfl_xor(rs0, 32);
  rs1 += __shfl_xor(rs1, 16); rs1 += __shfl_xor(rs1, 32);
  if (l < 16){ rsum[w*2][q][l] = rs0; rsum[w*2+1][q][l] = rs1; }
  __syncthreads();

  float t0 = rsum[w*2  ][0][r16] + rsum[w*2  ][1][r16]
           + rsum[w*2  ][2][r16] + rsum[w*2  ][3][r16];
  float t1 = rsum[w*2+1][0][r16] + rsum[w*2+1][1][r16]
           + rsum[w*2+1][2][r16] + rsum[w*2+1][3][r16];
  float inv0[4], inv1[4];
#pragma unroll
  for (int r=0;r<4;r++){ inv0[r] = 1.0f / __shfl(t0, g*4 + r);
                         inv1[r] = 1.0f / __shfl(t1, g*4 + r); }

  // ---- 2 combine rounds (full tile per round), red on staging LDS ----
  f32x4* red = (f32x4*)smem;                       // [w][c16][q][l]
#define RED(W_,C_,Q_,L_) red[(((W_)*16 + (C_))*4 + (Q_))*64 + (L_)]
#pragma unroll
  for (int s = 0; s < 2; ++s){
    f32x4* accp = s ? acc1 : acc0;
#pragma unroll
    for (int c=0;c<16;c++) RED(w,c,q,l) = accp[c];
    __syncthreads();
    const float* inv_ = s ? inv1 : inv0;
    float* outB = out + (size_t)(b*NN + n0 + w*32 + s*16)*FD;
#pragma unroll
    for (int i=0;i<4;i++){
      const int c = q*4 + i;
      f32x4 v = RED(w,c,0,l) + RED(w,c,1,l) + RED(w,c,2,l) + RED(w,c,3,l);
#pragma unroll
      for (int r=0;r<4;r++){
        float o = v[r] * inv_[r];
        o = o > 0.f ? o : (__expf(o) - 1.f);       // ELU
        __builtin_nontemporal_store(o,
            &outB[(size_t)(g*4 + r)*FD + c*16 + r16]);
      }
    }
    __syncthreads();
  }
#undef RED
}

// ---------------------------------------------------------------------------
extern "C" void kernel_launch(void* const* d_in, const int* in_sizes, int n_in,
                              void* d_out, int out_size, void* d_ws, size_t ws_size,
                              hipStream_t stream)
{
  const float* x   = (const float*)d_in[0];
  const int*   adj = (const int*)  d_in[1];
  const float* W   = (const float*)d_in[2];
  const float* a   = (const float*)d_in[3];
  float* out = (float*)d_out;

  char* ws = (char*)d_ws;
  size_t off = 0;
  auto alloc = [&](size_t bytes)->char*{
    char* p = ws + off; off += (bytes + 255) & ~(size_t)255; return p;
  };
  unsigned short* WT    = (unsigned short*)alloc((size_t)FD*FD*2);
  float*          w_src = (float*)alloc(FD*4);
  float*          w_dst = (float*)alloc(FD*4);
  float*          e_src = (float*)alloc((size_t)BATCH*NN*4);
  float*          e_dst = (float*)alloc((size_t)BATCH*NN*4);
  unsigned short* hT    = (unsigned short*)alloc((size_t)BATCH*NN*FD*2);

  prep_w   <<<FD,              64,  0, stream>>>(W, a, w_src, w_dst, WT);
  gemm_he  <<<(BATCH*NN)/64,   256, 0, stream>>>(x, w_src, w_dst, WT, hT, e_src, e_dst);
  gat_fused<<<(BATCH*NN)/64,   512, 0, stream>>>(adj, e_src, e_dst, hT, out);
}